// Round 2
// baseline (1037.076 us; speedup 1.0000x reference)
//
#include <hip/hip_runtime.h>

typedef unsigned short u16;
typedef __attribute__((ext_vector_type(8))) short short8;
typedef __attribute__((ext_vector_type(4))) float f32x4;

__device__ __forceinline__ u16 f2bf(float f) {
    unsigned u = __builtin_bit_cast(unsigned, f);
    u += 0x7FFFu + ((u >> 16) & 1u);
    return (u16)(u >> 16);
}
__device__ __forceinline__ float bf2f(u16 h) {
    unsigned u = ((unsigned)h) << 16;
    return __builtin_bit_cast(float, u);
}

#define GLD_LDS(g, l) \
    __builtin_amdgcn_global_load_lds((const __attribute__((address_space(1))) void*)(g), \
                                     (__attribute__((address_space(3))) void*)(l), 16, 0, 0)

// XCD-aware bijective block swizzle (T1). XCD == flat % 8; remap so each XCD
// owns a contiguous chunk of tiles. Requires nwg % 8 == 0 (1024, 1024, 128).
__device__ __forceinline__ void xcd_swizzle(int& bx, int& by) {
    const int nwg = gridDim.x * gridDim.y;
    const int flat = blockIdx.y * gridDim.x + blockIdx.x;
    const int cpx = nwg >> 3;
    const int nf = (flat & 7) * cpx + (flat >> 3);
    bx = nf % gridDim.x;
    by = nf / gridDim.x;
}

// ---------------------------------------------------------------------------
// Dtype sniff: flag=1 -> inputs are float32; flag=0 -> inputs are bf16.
// ---------------------------------------------------------------------------
__global__ void sniff_dtype(const u16* __restrict__ wq, int* __restrict__ flag) {
    __shared__ int cnt;
    if (threadIdx.x == 0) cnt = 0;
    __syncthreads();
    int local = 0;
    for (int i = threadIdx.x; i < 1024; i += 256) {
        const int e = (wq[i] >> 7) & 0xFF;
        if (e >= 0x81) local++;
    }
    atomicAdd(&cnt, local);
    __syncthreads();
    if (threadIdx.x == 0) *flag = (cnt >= 32) ? 1 : 0;
}

// ---------------------------------------------------------------------------
// Convert-or-copy to bf16
// ---------------------------------------------------------------------------
__global__ void cvt_copy(const void* __restrict__ in, u16* __restrict__ out, int n,
                         const int* __restrict__ flag) {
    const int stride = gridDim.x * 256;
    int i = blockIdx.x * 256 + threadIdx.x;
    if (*flag) {
        const float* p = (const float*)in;
        for (; i < n; i += stride) out[i] = f2bf(p[i]);
    } else {
        const u16* p = (const u16*)in;
        for (; i < n; i += stride) out[i] = p[i];
    }
}

// ---------------------------------------------------------------------------
// 1024x1024 transpose with convert-to-bf16
// ---------------------------------------------------------------------------
__global__ void transpose_cvt(const void* __restrict__ in, u16* __restrict__ out,
                              const int* __restrict__ flag) {
    __shared__ u16 t[32][33];
    const int x0 = blockIdx.x * 32, y0 = blockIdx.y * 32;
    const int tx = threadIdx.x, ty = threadIdx.y;
    if (*flag) {
        const float* p = (const float*)in;
        for (int dy = ty; dy < 32; dy += 8)
            t[dy][tx] = f2bf(p[(size_t)(y0 + dy) * 1024 + x0 + tx]);
    } else {
        const u16* p = (const u16*)in;
        for (int dy = ty; dy < 32; dy += 8)
            t[dy][tx] = p[(size_t)(y0 + dy) * 1024 + x0 + tx];
    }
    __syncthreads();
    for (int dy = ty; dy < 32; dy += 8)
        out[(size_t)(x0 + dy) * 1024 + y0 + tx] = t[tx][dy];
}

// ---------------------------------------------------------------------------
// bf16 GEMM: C[M,N] = A[M,K] @ BT[N,K]^T. 128x128 tile, BK=32, 4 waves.
// 2-phase double-buffered: prefetch next K-step during MFMA of current;
// ONE __syncthreads per step (its implicit vmcnt(0)+lgkmcnt(0) is exactly
// the prefetch/read-ready sync). LDS chunk: chunk(kc,m) at kc*128+m.
// ---------------------------------------------------------------------------
__global__ void gemm_bt(const u16* __restrict__ A, const u16* __restrict__ BT,
                        u16* __restrict__ C, int K, int lda, int ldb, int ldc) {
    __shared__ __align__(16) u16 As[2][512 * 8];
    __shared__ __align__(16) u16 Bs[2][512 * 8];
    const int tid = threadIdx.x;
    const int wave = tid >> 6, lane = tid & 63, quad = lane >> 4, r = lane & 15;
    const int wm = (wave >> 1) * 64, wn = (wave & 1) * 64;
    int bx, by;
    xcd_swizzle(bx, by);
    const long m0 = (long)by * 128, n0 = (long)bx * 128;

    f32x4 acc[4][4] = {};
    const int c0 = wave * 64 + lane, c1 = (wave + 4) * 64 + lane;
    const int kc0 = c0 >> 7, mm0 = c0 & 127, kc1 = c1 >> 7, mm1 = c1 & 127;
    const u16* ga0 = A + (m0 + mm0) * (long)lda + kc0 * 8;
    const u16* ga1 = A + (m0 + mm1) * (long)lda + kc1 * 8;
    const u16* gb0 = BT + (n0 + mm0) * (long)ldb + kc0 * 8;
    const u16* gb1 = BT + (n0 + mm1) * (long)ldb + kc1 * 8;

    // prologue: stage k0=0 into buffer 0
    GLD_LDS(ga0, &As[0][wave * 64 * 8]);
    GLD_LDS(ga1, &As[0][(wave + 4) * 64 * 8]);
    GLD_LDS(gb0, &Bs[0][wave * 64 * 8]);
    GLD_LDS(gb1, &Bs[0][(wave + 4) * 64 * 8]);
    __syncthreads();

    for (int k0 = 0; k0 < K; k0 += 32) {
        const int cur = (k0 >> 5) & 1, nxt = cur ^ 1;
        const int k1 = k0 + 32;
        if (k1 < K) {
            GLD_LDS(ga0 + k1, &As[nxt][wave * 64 * 8]);
            GLD_LDS(ga1 + k1, &As[nxt][(wave + 4) * 64 * 8]);
            GLD_LDS(gb0 + k1, &Bs[nxt][wave * 64 * 8]);
            GLD_LDS(gb1 + k1, &Bs[nxt][(wave + 4) * 64 * 8]);
        }
        short8 af[4], bfr[4];
#pragma unroll
        for (int mt = 0; mt < 4; mt++)
            af[mt] = *(const short8*)&As[cur][(quad * 128 + wm + mt * 16 + r) * 8];
#pragma unroll
        for (int nt = 0; nt < 4; nt++)
            bfr[nt] = *(const short8*)&Bs[cur][(quad * 128 + wn + nt * 16 + r) * 8];
#pragma unroll
        for (int mt = 0; mt < 4; mt++)
#pragma unroll
            for (int nt = 0; nt < 4; nt++)
                acc[mt][nt] = __builtin_amdgcn_mfma_f32_16x16x32_bf16(
                    af[mt], bfr[nt], acc[mt][nt], 0, 0, 0);
        __syncthreads();
    }
#pragma unroll
    for (int mt = 0; mt < 4; mt++)
#pragma unroll
        for (int nt = 0; nt < 4; nt++)
#pragma unroll
            for (int reg = 0; reg < 4; reg++) {
                const long row = m0 + wm + mt * 16 + quad * 4 + reg;
                const long col = n0 + wn + nt * 16 + r;
                C[row * (long)ldc + col] = f2bf(acc[mt][nt][reg]);
            }
}

// ---------------------------------------------------------------------------
// Q projection GEMM, dtype-templated on the A operand (x). WANT=0: A bf16
// (GLD_LDS staging, dbuf prefetch). WANT=1: A f32 — T14 split: issue global
// loads BEFORE the MFMA cluster, cvt+ds_write AFTER it (latency hides under
// MFMA). Fixed M=16384, N=1024, K=1024. Early-exits unless *flag == WANT.
// ---------------------------------------------------------------------------
template <int WANT>
__global__ void gemm_qa(const void* __restrict__ Av, long abase,
                        const u16* __restrict__ BT, u16* __restrict__ C,
                        const int* __restrict__ flag) {
    if (*flag != WANT) return;
    __shared__ __align__(16) u16 As[2][512 * 8];
    __shared__ __align__(16) u16 Bs[2][512 * 8];
    const int tid = threadIdx.x;
    const int wave = tid >> 6, lane = tid & 63, quad = lane >> 4, r = lane & 15;
    const int wm = (wave >> 1) * 64, wn = (wave & 1) * 64;
    int bx, by;
    xcd_swizzle(bx, by);
    const long m0 = (long)by * 128, n0 = (long)bx * 128;

    f32x4 acc[4][4] = {};
    const int c0 = wave * 64 + lane, c1 = (wave + 4) * 64 + lane;
    const int kc0 = c0 >> 7, mm0 = c0 & 127, kc1 = c1 >> 7, mm1 = c1 & 127;
    const long ra0 = (m0 + mm0) * 1024L + kc0 * 8;
    const long ra1 = (m0 + mm1) * 1024L + kc1 * 8;
    const u16* gb0 = BT + (n0 + mm0) * 1024L + kc0 * 8;
    const u16* gb1 = BT + (n0 + mm1) * 1024L + kc1 * 8;

    // prologue: stage k0=0 into buffer 0
    if (WANT == 0) {
        const u16* A = (const u16*)Av + abase;
        GLD_LDS(A + ra0, &As[0][wave * 64 * 8]);
        GLD_LDS(A + ra1, &As[0][(wave + 4) * 64 * 8]);
    } else {
        const float* A = (const float*)Av + abase;
        const f32x4 p0 = *(const f32x4*)(A + ra0);
        const f32x4 p1 = *(const f32x4*)(A + ra0 + 4);
        const f32x4 p2 = *(const f32x4*)(A + ra1);
        const f32x4 p3 = *(const f32x4*)(A + ra1 + 4);
        short8 h0, h1;
#pragma unroll
        for (int j = 0; j < 4; j++) {
            h0[j] = (short)f2bf(p0[j]);
            h0[j + 4] = (short)f2bf(p1[j]);
            h1[j] = (short)f2bf(p2[j]);
            h1[j + 4] = (short)f2bf(p3[j]);
        }
        *(short8*)&As[0][c0 * 8] = h0;
        *(short8*)&As[0][c1 * 8] = h1;
    }
    GLD_LDS(gb0, &Bs[0][wave * 64 * 8]);
    GLD_LDS(gb1, &Bs[0][(wave + 4) * 64 * 8]);
    __syncthreads();

    for (int k0 = 0; k0 < 1024; k0 += 32) {
        const int cur = (k0 >> 5) & 1, nxt = cur ^ 1;
        const int k1 = k0 + 32;
        const bool have = (k1 < 1024);
        f32x4 p0, p1, p2, p3;
        if (have) {
            if (WANT == 0) {
                const u16* A = (const u16*)Av + abase;
                GLD_LDS(A + ra0 + k1, &As[nxt][wave * 64 * 8]);
                GLD_LDS(A + ra1 + k1, &As[nxt][(wave + 4) * 64 * 8]);
            } else {
                const float* A = (const float*)Av + abase;
                p0 = *(const f32x4*)(A + ra0 + k1);
                p1 = *(const f32x4*)(A + ra0 + k1 + 4);
                p2 = *(const f32x4*)(A + ra1 + k1);
                p3 = *(const f32x4*)(A + ra1 + k1 + 4);
            }
            GLD_LDS(gb0 + k1, &Bs[nxt][wave * 64 * 8]);
            GLD_LDS(gb1 + k1, &Bs[nxt][(wave + 4) * 64 * 8]);
        }
        short8 af[4], bfr[4];
#pragma unroll
        for (int mt = 0; mt < 4; mt++)
            af[mt] = *(const short8*)&As[cur][(quad * 128 + wm + mt * 16 + r) * 8];
#pragma unroll
        for (int nt = 0; nt < 4; nt++)
            bfr[nt] = *(const short8*)&Bs[cur][(quad * 128 + wn + nt * 16 + r) * 8];
#pragma unroll
        for (int mt = 0; mt < 4; mt++)
#pragma unroll
            for (int nt = 0; nt < 4; nt++)
                acc[mt][nt] = __builtin_amdgcn_mfma_f32_16x16x32_bf16(
                    af[mt], bfr[nt], acc[mt][nt], 0, 0, 0);
        if (WANT == 1 && have) {
            short8 h0, h1;
#pragma unroll
            for (int j = 0; j < 4; j++) {
                h0[j] = (short)f2bf(p0[j]);
                h0[j + 4] = (short)f2bf(p1[j]);
                h1[j] = (short)f2bf(p2[j]);
                h1[j + 4] = (short)f2bf(p3[j]);
            }
            *(short8*)&As[nxt][c0 * 8] = h0;
            *(short8*)&As[nxt][c1 * 8] = h1;
        }
        __syncthreads();
    }
#pragma unroll
    for (int mt = 0; mt < 4; mt++)
#pragma unroll
        for (int nt = 0; nt < 4; nt++)
#pragma unroll
            for (int reg = 0; reg < 4; reg++) {
                const long row = m0 + wm + mt * 16 + quad * 4 + reg;
                const long col = n0 + wn + nt * 16 + r;
                C[row * 1024L + col] = f2bf(acc[mt][nt][reg]);
            }
}

// ---------------------------------------------------------------------------
// Final GEMM: out[m,n] = sum_{k<1024} S[m,k]*BT[n,k] + Tm[m,k]*BT[n,1024+k].
// 2-phase double-buffered like gemm_bt. M=16384, N=1024, ldb=2048.
// ---------------------------------------------------------------------------
__global__ void gemm_final(const u16* __restrict__ S, const u16* Tm,
                           const u16* __restrict__ BT, void* __restrict__ outv,
                           long base, const int* __restrict__ flag) {
    __shared__ __align__(16) u16 As[2][512 * 8];
    __shared__ __align__(16) u16 Bs[2][512 * 8];
    const int tid = threadIdx.x;
    const int wave = tid >> 6, lane = tid & 63, quad = lane >> 4, r = lane & 15;
    const int wm = (wave >> 1) * 64, wn = (wave & 1) * 64;
    int bx, by;
    xcd_swizzle(bx, by);
    const long m0 = (long)by * 128, n0 = (long)bx * 128;

    f32x4 acc[4][4] = {};
    const int c0 = wave * 64 + lane, c1 = (wave + 4) * 64 + lane;
    const int kc0 = c0 >> 7, mm0 = c0 & 127, kc1 = c1 >> 7, mm1 = c1 & 127;
    const long ra0 = (m0 + mm0) * 1024L + kc0 * 8;
    const long ra1 = (m0 + mm1) * 1024L + kc1 * 8;
    const u16* gb0 = BT + (n0 + mm0) * 2048L + kc0 * 8;
    const u16* gb1 = BT + (n0 + mm1) * 2048L + kc1 * 8;

    // prologue: stage k0=0 (A source = S) into buffer 0
    GLD_LDS(S + ra0, &As[0][wave * 64 * 8]);
    GLD_LDS(S + ra1, &As[0][(wave + 4) * 64 * 8]);
    GLD_LDS(gb0, &Bs[0][wave * 64 * 8]);
    GLD_LDS(gb1, &Bs[0][(wave + 4) * 64 * 8]);
    __syncthreads();

    for (int k0 = 0; k0 < 2048; k0 += 32) {
        const int cur = (k0 >> 5) & 1, nxt = cur ^ 1;
        const int k1 = k0 + 32;
        if (k1 < 2048) {
            const u16* Ab = (k1 < 1024) ? S : (Tm - 1024);
            GLD_LDS(Ab + ra0 + k1, &As[nxt][wave * 64 * 8]);
            GLD_LDS(Ab + ra1 + k1, &As[nxt][(wave + 4) * 64 * 8]);
            GLD_LDS(gb0 + k1, &Bs[nxt][wave * 64 * 8]);
            GLD_LDS(gb1 + k1, &Bs[nxt][(wave + 4) * 64 * 8]);
        }
        short8 af[4], bfr[4];
#pragma unroll
        for (int mt = 0; mt < 4; mt++)
            af[mt] = *(const short8*)&As[cur][(quad * 128 + wm + mt * 16 + r) * 8];
#pragma unroll
        for (int nt = 0; nt < 4; nt++)
            bfr[nt] = *(const short8*)&Bs[cur][(quad * 128 + wn + nt * 16 + r) * 8];
#pragma unroll
        for (int mt = 0; mt < 4; mt++)
#pragma unroll
            for (int nt = 0; nt < 4; nt++)
                acc[mt][nt] = __builtin_amdgcn_mfma_f32_16x16x32_bf16(
                    af[mt], bfr[nt], acc[mt][nt], 0, 0, 0);
        __syncthreads();
    }
    if (*flag) {
        float* o = (float*)outv + base;
#pragma unroll
        for (int mt = 0; mt < 4; mt++)
#pragma unroll
            for (int nt = 0; nt < 4; nt++)
#pragma unroll
                for (int reg = 0; reg < 4; reg++)
                    o[(m0 + wm + mt * 16 + quad * 4 + reg) * 1024L + n0 + wn +
                      nt * 16 + r] = acc[mt][nt][reg];
    } else {
        u16* o = (u16*)outv + base;
#pragma unroll
        for (int mt = 0; mt < 4; mt++)
#pragma unroll
            for (int nt = 0; nt < 4; nt++)
#pragma unroll
                for (int reg = 0; reg < 4; reg++)
                    o[(m0 + wm + mt * 16 + quad * 4 + reg) * 1024L + n0 + wn +
                      nt * 16 + r] = f2bf(acc[mt][nt][reg]);
    }
}

// ---------------------------------------------------------------------------
// K/V projection from textc (bf16); Wk/Wv read per flag.
// Kp[b][g][80][64] (rows 77..79 = 0), VT[b][g][64][96] (cols 77..95 = 0).
// ---------------------------------------------------------------------------
__global__ void prep_kv(const u16* __restrict__ textc, const void* __restrict__ Wk,
                        const void* __restrict__ Wv, const int* __restrict__ flag,
                        u16* __restrict__ Kp, u16* __restrict__ VT) {
    const int c = blockIdx.x, g = blockIdx.y, b = blockIdx.z;
    const int tid = threadIdx.x;
    __shared__ u16 tl[16 * 1024];
    const int tok0 = c * 16;
    for (int idx = tid; idx < 16 * 1024; idx += 256) {
        const int t = idx >> 10, j = idx & 1023;
        const int tok = tok0 + t;
        tl[idx] = (tok < 77) ? textc[((size_t)b * 77 + tok) * 1024 + j] : (u16)0;
    }
    __syncthreads();
    const int d = tid & 63, tq = tid >> 6;
    float ak[4] = {0.f, 0.f, 0.f, 0.f}, av[4] = {0.f, 0.f, 0.f, 0.f};
    if (*flag) {
        const float* WkF = (const float*)Wk;
        const float* WvF = (const float*)Wv;
        for (int j = 0; j < 1024; j++) {
            const float wk = WkF[(size_t)j * 256 + g * 64 + d];
            const float wv = WvF[(size_t)j * 256 + g * 64 + d];
#pragma unroll
            for (int t2 = 0; t2 < 4; t2++) {
                const float xv = bf2f(tl[(tq + t2 * 4) * 1024 + j]);
                ak[t2] += xv * wk;
                av[t2] += xv * wv;
            }
        }
    } else {
        const u16* WkH = (const u16*)Wk;
        const u16* WvH = (const u16*)Wv;
        for (int j = 0; j < 1024; j++) {
            const float wk = bf2f(WkH[(size_t)j * 256 + g * 64 + d]);
            const float wv = bf2f(WvH[(size_t)j * 256 + g * 64 + d]);
#pragma unroll
            for (int t2 = 0; t2 < 4; t2++) {
                const float xv = bf2f(tl[(tq + t2 * 4) * 1024 + j]);
                ak[t2] += xv * wk;
                av[t2] += xv * wv;
            }
        }
    }
#pragma unroll
    for (int t2 = 0; t2 < 4; t2++) {
        const int tok = tok0 + tq + t2 * 4;
        if (tok < 80)
            Kp[((size_t)(b * 4 + g) * 80 + tok) * 64 + d] = f2bf(ak[t2]);
        VT[(size_t)(b * 4 + g) * 64 * 96 + (size_t)d * 96 + tok] = f2bf(av[t2]);
    }
}

// ---------------------------------------------------------------------------
// Attention core per wave: 16 queries x 77 tokens x one head. Includes a
// block barrier between the P LDS store and its A-fragment re-read (all 4
// waves call this uniformly).
// ---------------------------------------------------------------------------
__device__ __forceinline__ void attn_core(const short8 aq0, const short8 aq1,
                                          const u16* Kl, const u16* Vl, u16* Plw,
                                          const int quad, const int r, f32x4 o[4]) {
    f32x4 sc[5];
#pragma unroll
    for (int nt = 0; nt < 5; nt++) {
        f32x4 z = {0.f, 0.f, 0.f, 0.f};
        const short8 bk0 = *(const short8*)&Kl[(nt * 16 + r) * 72 + quad * 8];
        const short8 bk1 = *(const short8*)&Kl[(nt * 16 + r) * 72 + 32 + quad * 8];
        z = __builtin_amdgcn_mfma_f32_16x16x32_bf16(aq0, bk0, z, 0, 0, 0);
        z = __builtin_amdgcn_mfma_f32_16x16x32_bf16(aq1, bk1, z, 0, 0, 0);
        sc[nt] = z;
    }
#pragma unroll
    for (int reg = 0; reg < 4; reg++) {
        float v[5];
        float mx = -3e38f;
#pragma unroll
        for (int nt = 0; nt < 5; nt++) {
            float s = sc[nt][reg] * 0.125f;
            if (nt == 4 && r >= 13) s = -3e38f;  // tokens 77..79 masked
            v[nt] = s;
            mx = fmaxf(mx, s);
        }
#pragma unroll
        for (int off = 1; off < 16; off <<= 1) mx = fmaxf(mx, __shfl_xor(mx, off));
        float sum = 0.f;
#pragma unroll
        for (int nt = 0; nt < 5; nt++) {
            v[nt] = __expf(v[nt] - mx);
            sum += v[nt];
        }
#pragma unroll
        for (int off = 1; off < 16; off <<= 1) sum += __shfl_xor(sum, off);
        const float inv = 1.0f / sum;
#pragma unroll
        for (int nt = 0; nt < 5; nt++)
            Plw[(quad * 4 + reg) * 104 + nt * 16 + r] = f2bf(v[nt] * inv);
    }
    __syncthreads();  // P store -> cross-lane A-frag read
    const short8 ap0 = *(const short8*)&Plw[r * 104 + quad * 8];
    const short8 ap1 = *(const short8*)&Plw[r * 104 + 32 + quad * 8];
    const short8 ap2 = *(const short8*)&Plw[r * 104 + 64 + quad * 8];
#pragma unroll
    for (int nt = 0; nt < 4; nt++) {
        f32x4 z = {0.f, 0.f, 0.f, 0.f};
        const short8 bv0 = *(const short8*)&Vl[(nt * 16 + r) * 104 + quad * 8];
        const short8 bv1 = *(const short8*)&Vl[(nt * 16 + r) * 104 + 32 + quad * 8];
        const short8 bv2 = *(const short8*)&Vl[(nt * 16 + r) * 104 + 64 + quad * 8];
        z = __builtin_amdgcn_mfma_f32_16x16x32_bf16(ap0, bv0, z, 0, 0, 0);
        z = __builtin_amdgcn_mfma_f32_16x16x32_bf16(ap1, bv1, z, 0, 0, 0);
        z = __builtin_amdgcn_mfma_f32_16x16x32_bf16(ap2, bv2, z, 0, 0, 0);
        o[nt] = z;
    }
}

// ---------------------------------------------------------------------------
// Spatial (per batch): grid (16 qc, 16 h, 16 t). Q rows t*1024+hw -> S same.
// ---------------------------------------------------------------------------
__global__ void attn_spatial(const u16* __restrict__ Q, const u16* __restrict__ Kp,
                             const u16* __restrict__ VT, u16* __restrict__ S) {
    const int qc = blockIdx.x, h = blockIdx.y, t = blockIdx.z;
    const int g = h >> 2;
    __shared__ __align__(16) u16 Kl[80 * 72];
    __shared__ __align__(16) u16 Vl[64 * 104];
    __shared__ __align__(16) u16 Pl[4][16 * 104];
    const int tid = threadIdx.x;
    const int wave = tid >> 6, lane = tid & 63, quad = lane >> 4, r = lane & 15;

    const u16* Kg = Kp + (size_t)g * 80 * 64;
    for (int idx = tid; idx < 80 * 64; idx += 256)
        Kl[(idx >> 6) * 72 + (idx & 63)] = Kg[idx];
    const u16* Vg = VT + (size_t)g * 64 * 96;
    for (int idx = tid; idx < 64 * 96; idx += 256) {
        const int d = idx / 96, tk = idx - d * 96;
        Vl[d * 104 + tk] = Vg[idx];
    }
#pragma unroll
    for (int j = 0; j < 4; j++) Pl[wave][r * 104 + 80 + quad * 4 + j] = 0;
    __syncthreads();

    const size_t qrow = (size_t)t * 1024 + qc * 64 + wave * 16 + r;
    const u16* Qb = Q + qrow * 1024 + h * 64;
    const short8 aq0 = *(const short8*)(Qb + quad * 8);
    const short8 aq1 = *(const short8*)(Qb + 32 + quad * 8);

    f32x4 o[4];
    attn_core(aq0, aq1, Kl, Vl, Pl[wave], quad, r, o);

    const size_t srow0 = (size_t)t * 1024 + qc * 64 + wave * 16 + quad * 4;
#pragma unroll
    for (int nt = 0; nt < 4; nt++)
#pragma unroll
        for (int reg = 0; reg < 4; reg++)
            S[(srow0 + reg) * 1024 + h * 64 + nt * 16 + r] = f2bf(o[nt][reg]);
}

// ---------------------------------------------------------------------------
// Temporal (per batch), IN-PLACE on Q: block reads == block writes; reads
// staged to LDS before first barrier, writes after compute.
// ---------------------------------------------------------------------------
__global__ void attn_temporal(u16* Q, const u16* __restrict__ Kp,
                              const u16* __restrict__ VT) {
    const int hw0 = blockIdx.x * 4, h = blockIdx.y;
    const int g = h >> 2;
    __shared__ __align__(16) u16 Kl[80 * 72];
    __shared__ __align__(16) u16 Vl[64 * 104];
    __shared__ __align__(16) u16 Ql[4][16 * 72];
    __shared__ __align__(16) u16 Pl[4][16 * 104];
    const int tid = threadIdx.x;
    const int wave = tid >> 6, lane = tid & 63, quad = lane >> 4, r = lane & 15;

    const u16* Kg = Kp + (size_t)g * 80 * 64;
    for (int idx = tid; idx < 80 * 64; idx += 256)
        Kl[(idx >> 6) * 72 + (idx & 63)] = Kg[idx];
    const u16* Vg = VT + (size_t)g * 64 * 96;
    for (int idx = tid; idx < 64 * 96; idx += 256) {
        const int d = idx / 96, tk = idx - d * 96;
        Vl[d * 104 + tk] = Vg[idx];
    }
    for (int idx = tid; idx < 4096; idx += 256) {
        const int hwl = idx >> 10, t = (idx >> 6) & 15, d = idx & 63;
        Ql[hwl][t * 72 + d] = Q[((size_t)t * 1024 + hw0 + hwl) * 1024 + h * 64 + d];
    }
#pragma unroll
    for (int j = 0; j < 4; j++) Pl[wave][r * 104 + 80 + quad * 4 + j] = 0;
    __syncthreads();

    const short8 aq0 = *(const short8*)&Ql[wave][r * 72 + quad * 8];
    const short8 aq1 = *(const short8*)&Ql[wave][r * 72 + 32 + quad * 8];

    f32x4 o[4];
    attn_core(aq0, aq1, Kl, Vl, Pl[wave], quad, r, o);

    const int hw = hw0 + wave;
#pragma unroll
    for (int nt = 0; nt < 4; nt++)
#pragma unroll
        for (int reg = 0; reg < 4; reg++)
            Q[((size_t)(quad * 4 + reg) * 1024 + hw) * 1024 + h * 64 + nt * 16 + r] =
                f2bf(o[nt][reg]);
}

// ---------------------------------------------------------------------------
// ws layout (bytes), total ~80.2 MB:
//   0         flag (64B)
//   64        WqT   2,097,152
//   2,097,216 WoT   2,097,152
//   4,194,368 Wstc  4,194,304
//   8,388,672 W12T  4,194,304
//  12,582,976 textc   315,392
//  12,898,368 Kp       81,920
//  12,980,288 VT       98,304
//  13,078,592 Q    33,554,432
//  46,633,024 S    33,554,432
// ---------------------------------------------------------------------------
extern "C" void kernel_launch(void* const* d_in, const int* in_sizes, int n_in,
                              void* d_out, int out_size, void* d_ws, size_t ws_size,
                              hipStream_t stream) {
    const void* x    = d_in[0];
    const void* text = d_in[1];
    const void* Wq   = d_in[5];
    const void* Wk   = d_in[6];
    const void* Wv   = d_in[7];
    const void* Wo   = d_in[8];
    const void* Wst  = d_in[9];
    char* ws = (char*)d_ws;

    int* flag  = (int*)(ws);
    u16* WqT   = (u16*)(ws + 64);
    u16* WoT   = (u16*)(ws + 2097216);
    u16* Wstc  = (u16*)(ws + 4194368);
    u16* W12T  = (u16*)(ws + 8388672);
    u16* textc = (u16*)(ws + 12582976);
    u16* Kp    = (u16*)(ws + 12898368);
    u16* VTb   = (u16*)(ws + 12980288);
    u16* Qws   = (u16*)(ws + 13078592);
    u16* Sws   = (u16*)(ws + 46633024);

    sniff_dtype<<<1, 256, 0, stream>>>((const u16*)Wq, flag);
    cvt_copy<<<256, 256, 0, stream>>>(text, textc, 157696, flag);
    cvt_copy<<<1024, 256, 0, stream>>>(Wst, Wstc, 2097152, flag);
    transpose_cvt<<<dim3(32, 32), dim3(32, 8), 0, stream>>>(Wq, WqT, flag);
    transpose_cvt<<<dim3(32, 32), dim3(32, 8), 0, stream>>>(Wo, WoT, flag);
    // W12T[n][k'] = (Wst @ Wo)[k'][n]  (M=1024, N=2048, K=1024)
    gemm_bt<<<dim3(16, 8), 256, 0, stream>>>(WoT, Wstc, W12T, 1024, 1024, 1024, 2048);
    prep_kv<<<dim3(6, 4, 2), 256, 0, stream>>>(textc, Wk, Wv, flag, Kp, VTb);

    for (int b = 0; b < 2; b++) {
        const long xbase = (long)b * 16777216;
        const u16* Kpb = Kp + (size_t)b * 20480;
        const u16* VTp = VTb + (size_t)b * 24576;

        // Q_b = x_b @ Wq (both dtype variants launched; device picks)
        gemm_qa<0><<<dim3(8, 128), 256, 0, stream>>>(x, xbase, WqT, Qws, flag);
        gemm_qa<1><<<dim3(8, 128), 256, 0, stream>>>(x, xbase, WqT, Qws, flag);
        // spatial attention: Q -> S
        attn_spatial<<<dim3(16, 16, 16), 256, 0, stream>>>(Qws, Kpb, VTp, Sws);
        // temporal attention: in-place Q -> Tm
        attn_temporal<<<dim3(256, 16), 256, 0, stream>>>(Qws, Kpb, VTp);
        // out_b = S@W1 + Tm@W2 (writes d_out only)
        gemm_final<<<dim3(8, 128), 256, 0, stream>>>(Sws, Qws, W12T, d_out, xbase, flag);
    }
}

// Round 4
// 870.645 us; speedup vs baseline: 1.1912x; 1.1912x over previous
//
#include <hip/hip_runtime.h>

typedef unsigned short u16;
typedef __attribute__((ext_vector_type(8))) short short8;
typedef __attribute__((ext_vector_type(4))) float f32x4;

__device__ __forceinline__ u16 f2bf(float f) {
    unsigned u = __builtin_bit_cast(unsigned, f);
    u += 0x7FFFu + ((u >> 16) & 1u);
    return (u16)(u >> 16);
}
__device__ __forceinline__ float bf2f(u16 h) {
    unsigned u = ((unsigned)h) << 16;
    return __builtin_bit_cast(float, u);
}

#define GLD_LDS(g, l) \
    __builtin_amdgcn_global_load_lds((const __attribute__((address_space(1))) void*)(g), \
                                     (__attribute__((address_space(3))) void*)(l), 16, 0, 0)

// Counted vmcnt (T4): keep prefetch in flight across barriers.
#define WAITV(n) asm volatile("s_waitcnt vmcnt(" #n ")" ::: "memory")
// Raw barrier with compiler memory fences on both sides (no vmcnt drain).
#define BARM()                                  \
    do {                                        \
        asm volatile("" ::: "memory");          \
        __builtin_amdgcn_s_barrier();           \
        asm volatile("" ::: "memory");          \
    } while (0)

// XCD-aware bijective block swizzle (T1). XCD == flat % 8; remap so each XCD
// owns a contiguous chunk of tiles. Requires nwg % 8 == 0 (256, 128 here).
__device__ __forceinline__ void xcd_swizzle(int& bx, int& by) {
    const int nwg = gridDim.x * gridDim.y;
    const int flat = blockIdx.y * gridDim.x + blockIdx.x;
    const int cpx = nwg >> 3;
    const int nf = (flat & 7) * cpx + (flat >> 3);
    bx = nf % gridDim.x;
    by = nf / gridDim.x;
}

// ---------------------------------------------------------------------------
// Dtype sniff: flag=1 -> inputs are float32; flag=0 -> inputs are bf16.
// ---------------------------------------------------------------------------
__global__ void sniff_dtype(const u16* __restrict__ wq, int* __restrict__ flag) {
    __shared__ int cnt;
    if (threadIdx.x == 0) cnt = 0;
    __syncthreads();
    int local = 0;
    for (int i = threadIdx.x; i < 1024; i += 256) {
        const int e = (wq[i] >> 7) & 0xFF;
        if (e >= 0x81) local++;
    }
    atomicAdd(&cnt, local);
    __syncthreads();
    if (threadIdx.x == 0) *flag = (cnt >= 32) ? 1 : 0;
}

// ---------------------------------------------------------------------------
// Convert-or-copy to bf16 (scalar; small inputs only)
// ---------------------------------------------------------------------------
__global__ void cvt_copy(const void* __restrict__ in, u16* __restrict__ out, int n,
                         const int* __restrict__ flag) {
    const int stride = gridDim.x * 256;
    int i = blockIdx.x * 256 + threadIdx.x;
    if (*flag) {
        const float* p = (const float*)in;
        for (; i < n; i += stride) out[i] = f2bf(p[i]);
    } else {
        const u16* p = (const u16*)in;
        for (; i < n; i += stride) out[i] = p[i];
    }
}

// ---------------------------------------------------------------------------
// Vectorized convert-or-copy with element offset (for x_b -> bf16 scratch).
// n must be a multiple of 8.
// ---------------------------------------------------------------------------
__global__ void cvt_copy8(const void* __restrict__ in, long off,
                          u16* __restrict__ out, long n,
                          const int* __restrict__ flag) {
    const long stride = (long)gridDim.x * 256 * 8;
    long i = ((long)blockIdx.x * 256 + threadIdx.x) * 8;
    if (*flag) {
        const float* p = (const float*)in + off;
        for (; i < n; i += stride) {
            const f32x4 a = *(const f32x4*)(p + i);
            const f32x4 b = *(const f32x4*)(p + i + 4);
            short8 h;
#pragma unroll
            for (int j = 0; j < 4; j++) {
                h[j] = (short)f2bf(a[j]);
                h[j + 4] = (short)f2bf(b[j]);
            }
            *(short8*)(out + i) = h;
        }
    } else {
        const u16* p = (const u16*)in + off;
        for (; i < n; i += stride) *(short8*)(out + i) = *(const short8*)(p + i);
    }
}

// ---------------------------------------------------------------------------
// 1024x1024 transpose with convert-to-bf16
// ---------------------------------------------------------------------------
__global__ void transpose_cvt(const void* __restrict__ in, u16* __restrict__ out,
                              const int* __restrict__ flag) {
    __shared__ u16 t[32][33];
    const int x0 = blockIdx.x * 32, y0 = blockIdx.y * 32;
    const int tx = threadIdx.x, ty = threadIdx.y;
    if (*flag) {
        const float* p = (const float*)in;
        for (int dy = ty; dy < 32; dy += 8)
            t[dy][tx] = f2bf(p[(size_t)(y0 + dy) * 1024 + x0 + tx]);
    } else {
        const u16* p = (const u16*)in;
        for (int dy = ty; dy < 32; dy += 8)
            t[dy][tx] = p[(size_t)(y0 + dy) * 1024 + x0 + tx];
    }
    __syncthreads();
    for (int dy = ty; dy < 32; dy += 8)
        out[(size_t)(x0 + dy) * 1024 + y0 + tx] = t[tx][dy];
}

// ---------------------------------------------------------------------------
// bf16 GEMM (small, W12T precompute): C[M,N] = A[M,K] @ BT[N,K]^T.
// 128x128 tile, BK=32, 4 waves. Round-1 proven form (2 syncthreads/iter).
// ---------------------------------------------------------------------------
__global__ void gemm_bt(const u16* __restrict__ A, const u16* __restrict__ BT,
                        u16* __restrict__ C, int K, int lda, int ldb, int ldc) {
    __shared__ __align__(16) u16 As[512 * 8];
    __shared__ __align__(16) u16 Bs[512 * 8];
    const int tid = threadIdx.x;
    const int wave = tid >> 6, lane = tid & 63, quad = lane >> 4, r = lane & 15;
    const int wm = (wave >> 1) * 64, wn = (wave & 1) * 64;
    int bx, by;
    xcd_swizzle(bx, by);
    const long m0 = (long)by * 128, n0 = (long)bx * 128;

    f32x4 acc[4][4] = {};
    const int c0 = wave * 64 + lane, c1 = (wave + 4) * 64 + lane;
    const int kc0 = c0 >> 7, mm0 = c0 & 127, kc1 = c1 >> 7, mm1 = c1 & 127;
    const u16* ga0 = A + (m0 + mm0) * (long)lda + kc0 * 8;
    const u16* ga1 = A + (m0 + mm1) * (long)lda + kc1 * 8;
    const u16* gb0 = BT + (n0 + mm0) * (long)ldb + kc0 * 8;
    const u16* gb1 = BT + (n0 + mm1) * (long)ldb + kc1 * 8;

    for (int k0 = 0; k0 < K; k0 += 32) {
        GLD_LDS(ga0 + k0, &As[wave * 64 * 8]);
        GLD_LDS(ga1 + k0, &As[(wave + 4) * 64 * 8]);
        GLD_LDS(gb0 + k0, &Bs[wave * 64 * 8]);
        GLD_LDS(gb1 + k0, &Bs[(wave + 4) * 64 * 8]);
        __syncthreads();
        short8 af[4], bfr[4];
#pragma unroll
        for (int mt = 0; mt < 4; mt++)
            af[mt] = *(const short8*)&As[(quad * 128 + wm + mt * 16 + r) * 8];
#pragma unroll
        for (int nt = 0; nt < 4; nt++)
            bfr[nt] = *(const short8*)&Bs[(quad * 128 + wn + nt * 16 + r) * 8];
#pragma unroll
        for (int mt = 0; mt < 4; mt++)
#pragma unroll
            for (int nt = 0; nt < 4; nt++)
                acc[mt][nt] = __builtin_amdgcn_mfma_f32_16x16x32_bf16(
                    af[mt], bfr[nt], acc[mt][nt], 0, 0, 0);
        __syncthreads();
    }
#pragma unroll
    for (int mt = 0; mt < 4; mt++)
#pragma unroll
        for (int nt = 0; nt < 4; nt++)
#pragma unroll
            for (int reg = 0; reg < 4; reg++) {
                const long row = m0 + wm + mt * 16 + quad * 4 + reg;
                const long col = n0 + wn + nt * 16 + r;
                C[row * (long)ldc + col] = f2bf(acc[mt][nt][reg]);
            }
}

// ---------------------------------------------------------------------------
// Stage one 16KB half-tile (128 rows x 64 k, bf16) into chunk-layout LDS:
// element (kc,row) at lds[(kc*256+row)*8]. Per wave: 2 global_load_lds
// (dst is wave-uniform; 64 lanes cover 64 consecutive rows). src points at
// the tile origin (base + tile_row0*ld + k0).
// ---------------------------------------------------------------------------
__device__ __forceinline__ void stage_ht(const u16* __restrict__ src, long ld,
                                         u16* lds, int half, int wave, int lane) {
#pragma unroll
    for (int j = 0; j < 2; j++) {
        const int idx0 = j * 512 + wave * 64;
        const int kc = idx0 >> 7, ml0 = idx0 & 127;
        GLD_LDS(src + (long)(half * 128 + ml0 + lane) * ld + kc * 8,
                lds + (kc * 256 + half * 128 + ml0) * 8);
    }
}

// ---------------------------------------------------------------------------
// 256x256-tile deep-pipelined bf16 GEMM (T3+T4+T5 on conflict-free chunk LDS).
// MODE 0 (Q proj): C = A1[16384,1024] @ BT[1024,1024]^T, bf16 out (outv+0).
// MODE 1 (final):  out = S@W1 + Tm@W2 via A = [A1 | A2], BT[1024,2048],
//                  K=2048, out dtype per flag at outv+base.
// 512 threads = 8 waves (2M x 4N); per-wave output 128x64 (8x4 16x16 frags).
// LDS 128KB: dbuf x (A 32KB + B 32KB) per 64-K tile.
// Schedule per tile t (buf c=t&1): ph0 {stage (t+1).A0 -> buf n; vmcnt(2);
// barrier; read B frags + A quad0; MFMA}; ph1-3 {stage next half; read A
// quadN; MFMA}; barrier. Stages NEVER target the buffer being read; the
// vmcnt(2) at ph0 waits exactly the 8 loads of tile t (FIFO), leaving the
// 2 just-issued in flight. 2 barriers per 64-K tile.
// ---------------------------------------------------------------------------
template <int MODE>
__global__ __launch_bounds__(512, 2) void gemm256(
    const u16* __restrict__ A1, const u16* __restrict__ A2,
    const u16* __restrict__ BT, void* __restrict__ outv, long base,
    const int* __restrict__ flag) {
    __shared__ __align__(16) u16 As[2][8 * 256 * 8];
    __shared__ __align__(16) u16 Bs[2][8 * 256 * 8];
    const int tid = threadIdx.x;
    const int wave = tid >> 6, lane = tid & 63, quad = lane >> 4, r = lane & 15;
    const int wr = wave >> 2, wc = wave & 3;
    int bx, by;
    xcd_swizzle(bx, by);
    const long m0 = (long)by * 256, n0 = (long)bx * 256;
    const int ldb = MODE ? 2048 : 1024;
    const int NT = MODE ? 32 : 16;

    f32x4 acc[8][4] = {};

    // A-tile origin for tile index tt (MODE 1 switches source at tt==16)
    auto asrc = [&](int tt) -> const u16* {
        if (MODE == 0) return A1 + m0 * 1024 + (long)tt * 64;
        return (tt < 16) ? (A1 + m0 * 1024 + (long)tt * 64)
                         : (A2 + m0 * 1024 + (long)(tt - 16) * 64);
    };
    const u16* bbase = BT + n0 * (long)ldb;

    // prologue: stage tile 0 (4 half-tiles = 8 loads/wave) into buffer 0
    stage_ht(asrc(0), 1024, As[0], 0, wave, lane);
    stage_ht(asrc(0), 1024, As[0], 1, wave, lane);
    stage_ht(bbase, ldb, Bs[0], 0, wave, lane);
    stage_ht(bbase, ldb, Bs[0], 1, wave, lane);

#define QUADX(mb)                                                              \
    {                                                                          \
        short8 afx[2][2];                                                      \
        _Pragma("unroll") for (int mi = 0; mi < 2; mi++)                       \
            _Pragma("unroll") for (int ks = 0; ks < 2; ks++)                   \
                afx[mi][ks] = *(const short8*)&As[c][((ks * 4 + quad) * 256 +  \
                    wr * 128 + (mb + mi) * 16 + r) * 8];                       \
        __builtin_amdgcn_s_setprio(1);                                         \
        _Pragma("unroll") for (int mi = 0; mi < 2; mi++)                       \
            _Pragma("unroll") for (int nt = 0; nt < 4; nt++)                   \
                _Pragma("unroll") for (int ks = 0; ks < 2; ks++)               \
                    acc[mb + mi][nt] = __builtin_amdgcn_mfma_f32_16x16x32_bf16(\
                        afx[mi][ks], bf[nt][ks], acc[mb + mi][nt], 0, 0, 0);   \
        __builtin_amdgcn_s_setprio(0);                                         \
    }

#pragma unroll 2
    for (int t = 0; t < NT; t++) {
        const int c = t & 1, n = c ^ 1;
        const bool have = (t + 1 < NT);
        const u16* an = asrc(t + 1 < NT ? t + 1 : t);  // safe ptr when !have
        const u16* bn = bbase + (long)(t + 1) * 64;
        // phase 0: prefetch issue-first, counted wait, barrier, B + quad0
        if (have) {
            stage_ht(an, 1024, As[n], 0, wave, lane);
            WAITV(2);
        } else {
            WAITV(0);
        }
        BARM();
        short8 bf[4][2];
#pragma unroll
        for (int nt = 0; nt < 4; nt++)
#pragma unroll
            for (int ks = 0; ks < 2; ks++)
                bf[nt][ks] = *(const short8*)&Bs[c][((ks * 4 + quad) * 256 +
                                                     wc * 64 + nt * 16 + r) * 8];
        QUADX(0);
        // phase 1
        if (have) stage_ht(an, 1024, As[n], 1, wave, lane);
        QUADX(2);
        // phase 2
        if (have) stage_ht(bn, ldb, Bs[n], 0, wave, lane);
        QUADX(4);
        // phase 3
        if (have) stage_ht(bn, ldb, Bs[n], 1, wave, lane);
        QUADX(6);
        BARM();
    }
#undef QUADX

    if (MODE == 0) {
        u16* o = (u16*)outv;
#pragma unroll
        for (int mt = 0; mt < 8; mt++)
#pragma unroll
            for (int nt = 0; nt < 4; nt++)
#pragma unroll
                for (int reg = 0; reg < 4; reg++)
                    o[(m0 + wr * 128 + mt * 16 + quad * 4 + reg) * 1024L + n0 +
                      wc * 64 + nt * 16 + r] = f2bf(acc[mt][nt][reg]);
    } else if (*flag) {
        float* o = (float*)outv + base;
#pragma unroll
        for (int mt = 0; mt < 8; mt++)
#pragma unroll
            for (int nt = 0; nt < 4; nt++)
#pragma unroll
                for (int reg = 0; reg < 4; reg++)
                    o[(m0 + wr * 128 + mt * 16 + quad * 4 + reg) * 1024L + n0 +
                      wc * 64 + nt * 16 + r] = acc[mt][nt][reg];
    } else {
        u16* o = (u16*)outv + base;
#pragma unroll
        for (int mt = 0; mt < 8; mt++)
#pragma unroll
            for (int nt = 0; nt < 4; nt++)
#pragma unroll
                for (int reg = 0; reg < 4; reg++)
                    o[(m0 + wr * 128 + mt * 16 + quad * 4 + reg) * 1024L + n0 +
                      wc * 64 + nt * 16 + r] = f2bf(acc[mt][nt][reg]);
    }
}

// ---------------------------------------------------------------------------
// K/V projection from textc (bf16); Wk/Wv read per flag.
// Kp[b][g][80][64] (rows 77..79 = 0), VT[b][g][64][96] (cols 77..95 = 0).
// ---------------------------------------------------------------------------
__global__ void prep_kv(const u16* __restrict__ textc, const void* __restrict__ Wk,
                        const void* __restrict__ Wv, const int* __restrict__ flag,
                        u16* __restrict__ Kp, u16* __restrict__ VT) {
    const int c = blockIdx.x, g = blockIdx.y, b = blockIdx.z;
    const int tid = threadIdx.x;
    __shared__ u16 tl[16 * 1024];
    const int tok0 = c * 16;
    for (int idx = tid; idx < 16 * 1024; idx += 256) {
        const int t = idx >> 10, j = idx & 1023;
        const int tok = tok0 + t;
        tl[idx] = (tok < 77) ? textc[((size_t)b * 77 + tok) * 1024 + j] : (u16)0;
    }
    __syncthreads();
    const int d = tid & 63, tq = tid >> 6;
    float ak[4] = {0.f, 0.f, 0.f, 0.f}, av[4] = {0.f, 0.f, 0.f, 0.f};
    if (*flag) {
        const float* WkF = (const float*)Wk;
        const float* WvF = (const float*)Wv;
        for (int j = 0; j < 1024; j++) {
            const float wk = WkF[(size_t)j * 256 + g * 64 + d];
            const float wv = WvF[(size_t)j * 256 + g * 64 + d];
#pragma unroll
            for (int t2 = 0; t2 < 4; t2++) {
                const float xv = bf2f(tl[(tq + t2 * 4) * 1024 + j]);
                ak[t2] += xv * wk;
                av[t2] += xv * wv;
            }
        }
    } else {
        const u16* WkH = (const u16*)Wk;
        const u16* WvH = (const u16*)Wv;
        for (int j = 0; j < 1024; j++) {
            const float wk = bf2f(WkH[(size_t)j * 256 + g * 64 + d]);
            const float wv = bf2f(WvH[(size_t)j * 256 + g * 64 + d]);
#pragma unroll
            for (int t2 = 0; t2 < 4; t2++) {
                const float xv = bf2f(tl[(tq + t2 * 4) * 1024 + j]);
                ak[t2] += xv * wk;
                av[t2] += xv * wv;
            }
        }
    }
#pragma unroll
    for (int t2 = 0; t2 < 4; t2++) {
        const int tok = tok0 + tq + t2 * 4;
        if (tok < 80)
            Kp[((size_t)(b * 4 + g) * 80 + tok) * 64 + d] = f2bf(ak[t2]);
        VT[(size_t)(b * 4 + g) * 64 * 96 + (size_t)d * 96 + tok] = f2bf(av[t2]);
    }
}

// ---------------------------------------------------------------------------
// Attention core per wave: 16 queries x 77 tokens x one head. Includes a
// block barrier between the P LDS store and its A-fragment re-read (all 4
// waves call this uniformly).
// ---------------------------------------------------------------------------
__device__ __forceinline__ void attn_core(const short8 aq0, const short8 aq1,
                                          const u16* Kl, const u16* Vl, u16* Plw,
                                          const int quad, const int r, f32x4 o[4]) {
    f32x4 sc[5];
#pragma unroll
    for (int nt = 0; nt < 5; nt++) {
        f32x4 z = {0.f, 0.f, 0.f, 0.f};
        const short8 bk0 = *(const short8*)&Kl[(nt * 16 + r) * 72 + quad * 8];
        const short8 bk1 = *(const short8*)&Kl[(nt * 16 + r) * 72 + 32 + quad * 8];
        z = __builtin_amdgcn_mfma_f32_16x16x32_bf16(aq0, bk0, z, 0, 0, 0);
        z = __builtin_amdgcn_mfma_f32_16x16x32_bf16(aq1, bk1, z, 0, 0, 0);
        sc[nt] = z;
    }
#pragma unroll
    for (int reg = 0; reg < 4; reg++) {
        float v[5];
        float mx = -3e38f;
#pragma unroll
        for (int nt = 0; nt < 5; nt++) {
            float s = sc[nt][reg] * 0.125f;
            if (nt == 4 && r >= 13) s = -3e38f;  // tokens 77..79 masked
            v[nt] = s;
            mx = fmaxf(mx, s);
        }
#pragma unroll
        for (int off = 1; off < 16; off <<= 1) mx = fmaxf(mx, __shfl_xor(mx, off));
        float sum = 0.f;
#pragma unroll
        for (int nt = 0; nt < 5; nt++) {
            v[nt] = __expf(v[nt] - mx);
            sum += v[nt];
        }
#pragma unroll
        for (int off = 1; off < 16; off <<= 1) sum += __shfl_xor(sum, off);
        const float inv = 1.0f / sum;
#pragma unroll
        for (int nt = 0; nt < 5; nt++)
            Plw[(quad * 4 + reg) * 104 + nt * 16 + r] = f2bf(v[nt] * inv);
    }
    __syncthreads();  // P store -> cross-lane A-frag read
    const short8 ap0 = *(const short8*)&Plw[r * 104 + quad * 8];
    const short8 ap1 = *(const short8*)&Plw[r * 104 + 32 + quad * 8];
    const short8 ap2 = *(const short8*)&Plw[r * 104 + 64 + quad * 8];
#pragma unroll
    for (int nt = 0; nt < 4; nt++) {
        f32x4 z = {0.f, 0.f, 0.f, 0.f};
        const short8 bv0 = *(const short8*)&Vl[(nt * 16 + r) * 104 + quad * 8];
        const short8 bv1 = *(const short8*)&Vl[(nt * 16 + r) * 104 + 32 + quad * 8];
        const short8 bv2 = *(const short8*)&Vl[(nt * 16 + r) * 104 + 64 + quad * 8];
        z = __builtin_amdgcn_mfma_f32_16x16x32_bf16(ap0, bv0, z, 0, 0, 0);
        z = __builtin_amdgcn_mfma_f32_16x16x32_bf16(ap1, bv1, z, 0, 0, 0);
        z = __builtin_amdgcn_mfma_f32_16x16x32_bf16(ap2, bv2, z, 0, 0, 0);
        o[nt] = z;
    }
}

// ---------------------------------------------------------------------------
// Spatial (per batch): grid (16 qc, 16 h, 16 t). Q rows t*1024+hw -> S same.
// ---------------------------------------------------------------------------
__global__ void attn_spatial(const u16* __restrict__ Q, const u16* __restrict__ Kp,
                             const u16* __restrict__ VT, u16* __restrict__ S) {
    const int qc = blockIdx.x, h = blockIdx.y, t = blockIdx.z;
    const int g = h >> 2;
    __shared__ __align__(16) u16 Kl[80 * 72];
    __shared__ __align__(16) u16 Vl[64 * 104];
    __shared__ __align__(16) u16 Pl[4][16 * 104];
    const int tid = threadIdx.x;
    const int wave = tid >> 6, lane = tid & 63, quad = lane >> 4, r = lane & 15;

    const u16* Kg = Kp + (size_t)g * 80 * 64;
    for (int idx = tid; idx < 80 * 64; idx += 256)
        Kl[(idx >> 6) * 72 + (idx & 63)] = Kg[idx];
    const u16* Vg = VT + (size_t)g * 64 * 96;
    for (int idx = tid; idx < 64 * 96; idx += 256) {
        const int d = idx / 96, tk = idx - d * 96;
        Vl[d * 104 + tk] = Vg[idx];
    }
#pragma unroll
    for (int j = 0; j < 4; j++) Pl[wave][r * 104 + 80 + quad * 4 + j] = 0;
    __syncthreads();

    const size_t qrow = (size_t)t * 1024 + qc * 64 + wave * 16 + r;
    const u16* Qb = Q + qrow * 1024 + h * 64;
    const short8 aq0 = *(const short8*)(Qb + quad * 8);
    const short8 aq1 = *(const short8*)(Qb + 32 + quad * 8);

    f32x4 o[4];
    attn_core(aq0, aq1, Kl, Vl, Pl[wave], quad, r, o);

    const size_t srow0 = (size_t)t * 1024 + qc * 64 + wave * 16 + quad * 4;
#pragma unroll
    for (int nt = 0; nt < 4; nt++)
#pragma unroll
        for (int reg = 0; reg < 4; reg++)
            S[(srow0 + reg) * 1024 + h * 64 + nt * 16 + r] = f2bf(o[nt][reg]);
}

// ---------------------------------------------------------------------------
// Temporal (per batch), IN-PLACE on Q: block reads == block writes; reads
// staged to LDS before first barrier, writes after compute.
// ---------------------------------------------------------------------------
__global__ void attn_temporal(u16* Q, const u16* __restrict__ Kp,
                              const u16* __restrict__ VT) {
    const int hw0 = blockIdx.x * 4, h = blockIdx.y;
    const int g = h >> 2;
    __shared__ __align__(16) u16 Kl[80 * 72];
    __shared__ __align__(16) u16 Vl[64 * 104];
    __shared__ __align__(16) u16 Ql[4][16 * 72];
    __shared__ __align__(16) u16 Pl[4][16 * 104];
    const int tid = threadIdx.x;
    const int wave = tid >> 6, lane = tid & 63, quad = lane >> 4, r = lane & 15;

    const u16* Kg = Kp + (size_t)g * 80 * 64;
    for (int idx = tid; idx < 80 * 64; idx += 256)
        Kl[(idx >> 6) * 72 + (idx & 63)] = Kg[idx];
    const u16* Vg = VT + (size_t)g * 64 * 96;
    for (int idx = tid; idx < 64 * 96; idx += 256) {
        const int d = idx / 96, tk = idx - d * 96;
        Vl[d * 104 + tk] = Vg[idx];
    }
    for (int idx = tid; idx < 4096; idx += 256) {
        const int hwl = idx >> 10, t = (idx >> 6) & 15, d = idx & 63;
        Ql[hwl][t * 72 + d] = Q[((size_t)t * 1024 + hw0 + hwl) * 1024 + h * 64 + d];
    }
#pragma unroll
    for (int j = 0; j < 4; j++) Pl[wave][r * 104 + 80 + quad * 4 + j] = 0;
    __syncthreads();

    const short8 aq0 = *(const short8*)&Ql[wave][r * 72 + quad * 8];
    const short8 aq1 = *(const short8*)&Ql[wave][r * 72 + 32 + quad * 8];

    f32x4 o[4];
    attn_core(aq0, aq1, Kl, Vl, Pl[wave], quad, r, o);

    const int hw = hw0 + wave;
#pragma unroll
    for (int nt = 0; nt < 4; nt++)
#pragma unroll
        for (int reg = 0; reg < 4; reg++)
            Q[((size_t)(quad * 4 + reg) * 1024 + hw) * 1024 + h * 64 + nt * 16 + r] =
                f2bf(o[nt][reg]);
}

// ---------------------------------------------------------------------------
// ws layout (bytes), total ~80.2 MB:
//   0         flag (64B)
//   64        WqT   2,097,152
//   2,097,216 WoT   2,097,152
//   4,194,368 Wstc  4,194,304
//   8,388,672 W12T  4,194,304
//  12,582,976 textc   315,392
//  12,898,368 Kp       81,920
//  12,980,288 VT       98,304
//  13,078,592 Q    33,554,432
//  46,633,024 S    33,554,432  (also reused as per-batch x->bf16 scratch)
// ---------------------------------------------------------------------------
extern "C" void kernel_launch(void* const* d_in, const int* in_sizes, int n_in,
                              void* d_out, int out_size, void* d_ws, size_t ws_size,
                              hipStream_t stream) {
    const void* x    = d_in[0];
    const void* text = d_in[1];
    const void* Wq   = d_in[5];
    const void* Wk   = d_in[6];
    const void* Wv   = d_in[7];
    const void* Wo   = d_in[8];
    const void* Wst  = d_in[9];
    char* ws = (char*)d_ws;

    int* flag  = (int*)(ws);
    u16* WqT   = (u16*)(ws + 64);
    u16* WoT   = (u16*)(ws + 2097216);
    u16* Wstc  = (u16*)(ws + 4194368);
    u16* W12T  = (u16*)(ws + 8388672);
    u16* textc = (u16*)(ws + 12582976);
    u16* Kp    = (u16*)(ws + 12898368);
    u16* VTb   = (u16*)(ws + 12980288);
    u16* Qws   = (u16*)(ws + 13078592);
    u16* Sws   = (u16*)(ws + 46633024);

    sniff_dtype<<<1, 256, 0, stream>>>((const u16*)Wq, flag);
    cvt_copy<<<256, 256, 0, stream>>>(text, textc, 157696, flag);
    cvt_copy<<<1024, 256, 0, stream>>>(Wst, Wstc, 2097152, flag);
    transpose_cvt<<<dim3(32, 32), dim3(32, 8), 0, stream>>>(Wq, WqT, flag);
    transpose_cvt<<<dim3(32, 32), dim3(32, 8), 0, stream>>>(Wo, WoT, flag);
    // W12T[n][k'] = (Wst @ Wo)[k'][n]  (M=1024, N=2048, K=1024)
    gemm_bt<<<dim3(16, 8), 256, 0, stream>>>(WoT, Wstc, W12T, 1024, 1024, 1024, 2048);
    prep_kv<<<dim3(6, 4, 2), 256, 0, stream>>>(textc, Wk, Wv, flag, Kp, VTb);

    for (int b = 0; b < 2; b++) {
        const long xbase = (long)b * 16777216;
        const u16* Kpb = Kp + (size_t)b * 20480;
        const u16* VTp = VTb + (size_t)b * 24576;

        // x_b -> bf16 scratch (Sws; consumed by gemm256<0> before attn
        // overwrites it with S)
        cvt_copy8<<<2048, 256, 0, stream>>>(x, xbase, Sws, 16777216L, flag);
        // Q_b = xc @ Wq  (256^2 deep-pipelined)
        gemm256<0><<<dim3(4, 64), 512, 0, stream>>>(Sws, nullptr, WqT, Qws, 0, flag);
        // spatial attention: Q -> S (Sws)
        attn_spatial<<<dim3(16, 16, 16), 256, 0, stream>>>(Qws, Kpb, VTp, Sws);
        // temporal attention: in-place Q -> Tm
        attn_temporal<<<dim3(256, 16), 256, 0, stream>>>(Qws, Kpb, VTp);
        // out_b = S@W1 + Tm@W2 (256^2 deep-pipelined, writes d_out only)
        gemm256<1><<<dim3(4, 64), 512, 0, stream>>>(Sws, Qws, W12T, d_out, xbase, flag);
    }
}

// Round 5
// 782.490 us; speedup vs baseline: 1.3254x; 1.1127x over previous
//
#include <hip/hip_runtime.h>

typedef unsigned short u16;
typedef __attribute__((ext_vector_type(8))) short short8;
typedef __attribute__((ext_vector_type(4))) float f32x4;

__device__ __forceinline__ u16 f2bf(float f) {
    unsigned u = __builtin_bit_cast(unsigned, f);
    u += 0x7FFFu + ((u >> 16) & 1u);
    return (u16)(u >> 16);
}
__device__ __forceinline__ float bf2f(u16 h) {
    unsigned u = ((unsigned)h) << 16;
    return __builtin_bit_cast(float, u);
}

#define GLD_LDS(g, l) \
    __builtin_amdgcn_global_load_lds((const __attribute__((address_space(1))) void*)(g), \
                                     (__attribute__((address_space(3))) void*)(l), 16, 0, 0)

// Counted vmcnt (T4): keep prefetch in flight across barriers.
#define WAITV(n) asm volatile("s_waitcnt vmcnt(" #n ")" ::: "memory")
// Raw barrier with compiler memory fences on both sides (no vmcnt drain).
#define BARM()                                  \
    do {                                        \
        asm volatile("" ::: "memory");          \
        __builtin_amdgcn_s_barrier();           \
        asm volatile("" ::: "memory");          \
    } while (0)

// XCD-aware bijective block swizzle (T1). XCD == flat % 8; remap so each XCD
// owns a contiguous chunk of tiles. Requires nwg % 8 == 0.
__device__ __forceinline__ void xcd_swizzle(int& bx, int& by) {
    const int nwg = gridDim.x * gridDim.y;
    const int flat = blockIdx.y * gridDim.x + blockIdx.x;
    const int cpx = nwg >> 3;
    const int nf = (flat & 7) * cpx + (flat >> 3);
    bx = nf % gridDim.x;
    by = nf / gridDim.x;
}

// ---------------------------------------------------------------------------
// Dtype sniff: flag=1 -> inputs are float32; flag=0 -> inputs are bf16.
// ---------------------------------------------------------------------------
__global__ void sniff_dtype(const u16* __restrict__ wq, int* __restrict__ flag) {
    __shared__ int cnt;
    if (threadIdx.x == 0) cnt = 0;
    __syncthreads();
    int local = 0;
    for (int i = threadIdx.x; i < 1024; i += 256) {
        const int e = (wq[i] >> 7) & 0xFF;
        if (e >= 0x81) local++;
    }
    atomicAdd(&cnt, local);
    __syncthreads();
    if (threadIdx.x == 0) *flag = (cnt >= 32) ? 1 : 0;
}

// ---------------------------------------------------------------------------
// Vectorized convert-or-copy with element offset. n multiple of 8.
// ---------------------------------------------------------------------------
__global__ void cvt_copy8(const void* __restrict__ in, long off,
                          u16* __restrict__ out, long n,
                          const int* __restrict__ flag) {
    const long stride = (long)gridDim.x * 256 * 8;
    long i = ((long)blockIdx.x * 256 + threadIdx.x) * 8;
    if (*flag) {
        const float* p = (const float*)in + off;
        for (; i < n; i += stride) {
            const f32x4 a = *(const f32x4*)(p + i);
            const f32x4 b = *(const f32x4*)(p + i + 4);
            short8 h;
#pragma unroll
            for (int j = 0; j < 4; j++) {
                h[j] = (short)f2bf(a[j]);
                h[j + 4] = (short)f2bf(b[j]);
            }
            *(short8*)(out + i) = h;
        }
    } else {
        const u16* p = (const u16*)in + off;
        for (; i < n; i += stride) *(short8*)(out + i) = *(const short8*)(p + i);
    }
}

// ---------------------------------------------------------------------------
// 1024x1024 transpose with convert-to-bf16
// ---------------------------------------------------------------------------
__global__ void transpose_cvt(const void* __restrict__ in, u16* __restrict__ out,
                              const int* __restrict__ flag) {
    __shared__ u16 t[32][33];
    const int x0 = blockIdx.x * 32, y0 = blockIdx.y * 32;
    const int tx = threadIdx.x, ty = threadIdx.y;
    if (*flag) {
        const float* p = (const float*)in;
        for (int dy = ty; dy < 32; dy += 8)
            t[dy][tx] = f2bf(p[(size_t)(y0 + dy) * 1024 + x0 + tx]);
    } else {
        const u16* p = (const u16*)in;
        for (int dy = ty; dy < 32; dy += 8)
            t[dy][tx] = p[(size_t)(y0 + dy) * 1024 + x0 + tx];
    }
    __syncthreads();
    for (int dy = ty; dy < 32; dy += 8)
        out[(size_t)(x0 + dy) * 1024 + y0 + tx] = t[tx][dy];
}

// ---------------------------------------------------------------------------
// Wk/Wv transpose: in [1024 rows][256 cols] (dtype per flag) -> out[256][1024]
// bf16. Grid (8, 32), block (32, 8).
// ---------------------------------------------------------------------------
__global__ void transpose_kv(const void* __restrict__ in, u16* __restrict__ out,
                             const int* __restrict__ flag) {
    __shared__ u16 t[32][33];
    const int x0 = blockIdx.x * 32, y0 = blockIdx.y * 32;  // x: col, y: row
    const int tx = threadIdx.x, ty = threadIdx.y;
    if (*flag) {
        const float* p = (const float*)in;
        for (int dy = ty; dy < 32; dy += 8)
            t[dy][tx] = f2bf(p[(size_t)(y0 + dy) * 256 + x0 + tx]);
    } else {
        const u16* p = (const u16*)in;
        for (int dy = ty; dy < 32; dy += 8)
            t[dy][tx] = p[(size_t)(y0 + dy) * 256 + x0 + tx];
    }
    __syncthreads();
    for (int dy = ty; dy < 32; dy += 8)
        out[(size_t)(x0 + dy) * 1024 + y0 + tx] = t[tx][dy];
}

// ---------------------------------------------------------------------------
// text -> textp[2*128][1024] bf16, rows 77..127 of each batch zeroed.
// Zero A-rows make the KV GEMM output rows 77..127 exactly zero, which
// provides the Kp/VT tail padding for free. Grid 256 blocks x 128 threads.
// ---------------------------------------------------------------------------
__global__ void cvt_pad_text(const void* __restrict__ in, u16* __restrict__ out,
                             const int* __restrict__ flag) {
    const int row = blockIdx.x, b = row >> 7, t = row & 127;
    const int j = threadIdx.x * 8;
    short8 h = {0, 0, 0, 0, 0, 0, 0, 0};
    if (t < 77) {
        if (*flag) {
            const float* p = (const float*)in + ((size_t)(b * 77 + t)) * 1024 + j;
            const f32x4 a = *(const f32x4*)p;
            const f32x4 c = *(const f32x4*)(p + 4);
#pragma unroll
            for (int k = 0; k < 4; k++) {
                h[k] = (short)f2bf(a[k]);
                h[k + 4] = (short)f2bf(c[k]);
            }
        } else {
            h = *(const short8*)((const u16*)in + ((size_t)(b * 77 + t)) * 1024 + j);
        }
    }
    *(short8*)&out[(size_t)row * 1024 + j] = h;
}

// ---------------------------------------------------------------------------
// Kall[256][512] -> Kp[b][g][80][64], VT[b][g][64][96]. Grid (4 g, 2 b).
// Rows >=77 of Kall are zero, so tail padding needs no masking.
// ---------------------------------------------------------------------------
__global__ void repack_kv(const u16* __restrict__ Kall, u16* __restrict__ Kp,
                          u16* __restrict__ VT) {
    const int g = blockIdx.x, b = blockIdx.y;
    const int tid = threadIdx.x;
    for (int idx = tid; idx < 80 * 64; idx += 256) {
        const int tok = idx >> 6, d = idx & 63;
        Kp[((size_t)(b * 4 + g) * 80 + tok) * 64 + d] =
            Kall[(size_t)(b * 128 + tok) * 512 + g * 64 + d];
    }
    for (int idx = tid; idx < 64 * 96; idx += 256) {
        const int d = idx / 96, tok = idx - d * 96;
        VT[(size_t)(b * 4 + g) * 6144 + d * 96 + tok] =
            Kall[(size_t)(b * 128 + tok) * 512 + 256 + g * 64 + d];
    }
}

// ---------------------------------------------------------------------------
// bf16 GEMM (small precomputes): C[M,N] = A[M,K] @ BT[N,K]^T.
// 128x128 tile, BK=32, 4 waves. Proven 2-syncthreads form.
// ---------------------------------------------------------------------------
__global__ void gemm_bt(const u16* __restrict__ A, const u16* __restrict__ BT,
                        u16* __restrict__ C, int K, int lda, int ldb, int ldc) {
    __shared__ __align__(16) u16 As[512 * 8];
    __shared__ __align__(16) u16 Bs[512 * 8];
    const int tid = threadIdx.x;
    const int wave = tid >> 6, lane = tid & 63, quad = lane >> 4, r = lane & 15;
    const int wm = (wave >> 1) * 64, wn = (wave & 1) * 64;
    int bx, by;
    xcd_swizzle(bx, by);
    const long m0 = (long)by * 128, n0 = (long)bx * 128;

    f32x4 acc[4][4] = {};
    const int c0 = wave * 64 + lane, c1 = (wave + 4) * 64 + lane;
    const int kc0 = c0 >> 7, mm0 = c0 & 127, kc1 = c1 >> 7, mm1 = c1 & 127;
    const u16* ga0 = A + (m0 + mm0) * (long)lda + kc0 * 8;
    const u16* ga1 = A + (m0 + mm1) * (long)lda + kc1 * 8;
    const u16* gb0 = BT + (n0 + mm0) * (long)ldb + kc0 * 8;
    const u16* gb1 = BT + (n0 + mm1) * (long)ldb + kc1 * 8;

    for (int k0 = 0; k0 < K; k0 += 32) {
        GLD_LDS(ga0 + k0, &As[wave * 64 * 8]);
        GLD_LDS(ga1 + k0, &As[(wave + 4) * 64 * 8]);
        GLD_LDS(gb0 + k0, &Bs[wave * 64 * 8]);
        GLD_LDS(gb1 + k0, &Bs[(wave + 4) * 64 * 8]);
        __syncthreads();
        short8 af[4], bfr[4];
#pragma unroll
        for (int mt = 0; mt < 4; mt++)
            af[mt] = *(const short8*)&As[(quad * 128 + wm + mt * 16 + r) * 8];
#pragma unroll
        for (int nt = 0; nt < 4; nt++)
            bfr[nt] = *(const short8*)&Bs[(quad * 128 + wn + nt * 16 + r) * 8];
#pragma unroll
        for (int mt = 0; mt < 4; mt++)
#pragma unroll
            for (int nt = 0; nt < 4; nt++)
                acc[mt][nt] = __builtin_amdgcn_mfma_f32_16x16x32_bf16(
                    af[mt], bfr[nt], acc[mt][nt], 0, 0, 0);
        __syncthreads();
    }
#pragma unroll
    for (int mt = 0; mt < 4; mt++)
#pragma unroll
        for (int nt = 0; nt < 4; nt++)
#pragma unroll
            for (int reg = 0; reg < 4; reg++) {
                const long row = m0 + wm + mt * 16 + quad * 4 + reg;
                const long col = n0 + wn + nt * 16 + r;
                C[row * (long)ldc + col] = f2bf(acc[mt][nt][reg]);
            }
}

// ---------------------------------------------------------------------------
// Stage one 16KB half-tile (128 rows x 64 k, bf16) into chunk-layout LDS:
// element (kc,row) at lds[(kc*256+row)*8]. Per wave: 2 global_load_lds.
// ---------------------------------------------------------------------------
__device__ __forceinline__ void stage_ht(const u16* __restrict__ src, long ld,
                                         u16* lds, int half, int wave, int lane) {
#pragma unroll
    for (int j = 0; j < 2; j++) {
        const int idx0 = j * 512 + wave * 64;
        const int kc = idx0 >> 7, ml0 = idx0 & 127;
        GLD_LDS(src + (long)(half * 128 + ml0 + lane) * ld + kc * 8,
                lds + (kc * 256 + half * 128 + ml0) * 8);
    }
}

// ---------------------------------------------------------------------------
// 256x256-tile deep-pipelined bf16 GEMM (T3+T4+T5 on conflict-free chunk LDS).
// MODE 0 (Q proj): C = A1[16384,1024] @ BT[1024,1024]^T, bf16 out (outv+0).
// MODE 1 (final):  out = S@W1 + Tm@W2 via A = [A1 | A2], BT[1024,2048],
//                  K=2048, out dtype per flag at outv+base.
// 512 threads = 8 waves (2M x 4N); per-wave output 128x64 (8x4 16x16 frags).
// LDS 128KB: dbuf x (A 32KB + B 32KB) per 64-K tile.
// ---------------------------------------------------------------------------
template <int MODE>
__global__ __launch_bounds__(512, 2) void gemm256(
    const u16* __restrict__ A1, const u16* __restrict__ A2,
    const u16* __restrict__ BT, void* __restrict__ outv, long base,
    const int* __restrict__ flag) {
    __shared__ __align__(16) u16 As[2][8 * 256 * 8];
    __shared__ __align__(16) u16 Bs[2][8 * 256 * 8];
    const int tid = threadIdx.x;
    const int wave = tid >> 6, lane = tid & 63, quad = lane >> 4, r = lane & 15;
    const int wr = wave >> 2, wc = wave & 3;
    int bx, by;
    xcd_swizzle(bx, by);
    const long m0 = (long)by * 256, n0 = (long)bx * 256;
    const int ldb = MODE ? 2048 : 1024;
    const int NT = MODE ? 32 : 16;

    f32x4 acc[8][4] = {};

    auto asrc = [&](int tt) -> const u16* {
        if (MODE == 0) return A1 + m0 * 1024 + (long)tt * 64;
        return (tt < 16) ? (A1 + m0 * 1024 + (long)tt * 64)
                         : (A2 + m0 * 1024 + (long)(tt - 16) * 64);
    };
    const u16* bbase = BT + n0 * (long)ldb;

    // prologue: stage tile 0 (4 half-tiles = 8 loads/wave) into buffer 0
    stage_ht(asrc(0), 1024, As[0], 0, wave, lane);
    stage_ht(asrc(0), 1024, As[0], 1, wave, lane);
    stage_ht(bbase, ldb, Bs[0], 0, wave, lane);
    stage_ht(bbase, ldb, Bs[0], 1, wave, lane);

#define QUADX(mb)                                                              \
    {                                                                          \
        short8 afx[2][2];                                                      \
        _Pragma("unroll") for (int mi = 0; mi < 2; mi++)                       \
            _Pragma("unroll") for (int ks = 0; ks < 2; ks++)                   \
                afx[mi][ks] = *(const short8*)&As[c][((ks * 4 + quad) * 256 +  \
                    wr * 128 + (mb + mi) * 16 + r) * 8];                       \
        __builtin_amdgcn_s_setprio(1);                                         \
        _Pragma("unroll") for (int mi = 0; mi < 2; mi++)                       \
            _Pragma("unroll") for (int nt = 0; nt < 4; nt++)                   \
                _Pragma("unroll") for (int ks = 0; ks < 2; ks++)               \
                    acc[mb + mi][nt] = __builtin_amdgcn_mfma_f32_16x16x32_bf16(\
                        afx[mi][ks], bf[nt][ks], acc[mb + mi][nt], 0, 0, 0);   \
        __builtin_amdgcn_s_setprio(0);                                         \
    }

#pragma unroll 2
    for (int t = 0; t < NT; t++) {
        const int c = t & 1, n = c ^ 1;
        const bool have = (t + 1 < NT);
        const u16* an = asrc(t + 1 < NT ? t + 1 : t);  // safe ptr when !have
        const u16* bn = bbase + (long)(t + 1) * 64;
        // phase 0: prefetch issue-first, counted wait, barrier, B + quad0
        if (have) {
            stage_ht(an, 1024, As[n], 0, wave, lane);
            WAITV(2);
        } else {
            WAITV(0);
        }
        BARM();
        short8 bf[4][2];
#pragma unroll
        for (int nt = 0; nt < 4; nt++)
#pragma unroll
            for (int ks = 0; ks < 2; ks++)
                bf[nt][ks] = *(const short8*)&Bs[c][((ks * 4 + quad) * 256 +
                                                     wc * 64 + nt * 16 + r) * 8];
        QUADX(0);
        // phase 1
        if (have) stage_ht(an, 1024, As[n], 1, wave, lane);
        QUADX(2);
        // phase 2
        if (have) stage_ht(bn, ldb, Bs[n], 0, wave, lane);
        QUADX(4);
        // phase 3
        if (have) stage_ht(bn, ldb, Bs[n], 1, wave, lane);
        QUADX(6);
        BARM();
    }
#undef QUADX

    if (MODE == 0) {
        u16* o = (u16*)outv;
#pragma unroll
        for (int mt = 0; mt < 8; mt++)
#pragma unroll
            for (int nt = 0; nt < 4; nt++)
#pragma unroll
                for (int reg = 0; reg < 4; reg++)
                    o[(m0 + wr * 128 + mt * 16 + quad * 4 + reg) * 1024L + n0 +
                      wc * 64 + nt * 16 + r] = f2bf(acc[mt][nt][reg]);
    } else if (*flag) {
        float* o = (float*)outv + base;
#pragma unroll
        for (int mt = 0; mt < 8; mt++)
#pragma unroll
            for (int nt = 0; nt < 4; nt++)
#pragma unroll
                for (int reg = 0; reg < 4; reg++)
                    o[(m0 + wr * 128 + mt * 16 + quad * 4 + reg) * 1024L + n0 +
                      wc * 64 + nt * 16 + r] = acc[mt][nt][reg];
    } else {
        u16* o = (u16*)outv + base;
#pragma unroll
        for (int mt = 0; mt < 8; mt++)
#pragma unroll
            for (int nt = 0; nt < 4; nt++)
#pragma unroll
                for (int reg = 0; reg < 4; reg++)
                    o[(m0 + wr * 128 + mt * 16 + quad * 4 + reg) * 1024L + n0 +
                      wc * 64 + nt * 16 + r] = f2bf(acc[mt][nt][reg]);
    }
}

// ---------------------------------------------------------------------------
// Attention core per wave: 16 queries x 77 tokens x one head.
// ---------------------------------------------------------------------------
__device__ __forceinline__ void attn_core(const short8 aq0, const short8 aq1,
                                          const u16* Kl, const u16* Vl, u16* Plw,
                                          const int quad, const int r, f32x4 o[4]) {
    f32x4 sc[5];
#pragma unroll
    for (int nt = 0; nt < 5; nt++) {
        f32x4 z = {0.f, 0.f, 0.f, 0.f};
        const short8 bk0 = *(const short8*)&Kl[(nt * 16 + r) * 72 + quad * 8];
        const short8 bk1 = *(const short8*)&Kl[(nt * 16 + r) * 72 + 32 + quad * 8];
        z = __builtin_amdgcn_mfma_f32_16x16x32_bf16(aq0, bk0, z, 0, 0, 0);
        z = __builtin_amdgcn_mfma_f32_16x16x32_bf16(aq1, bk1, z, 0, 0, 0);
        sc[nt] = z;
    }
#pragma unroll
    for (int reg = 0; reg < 4; reg++) {
        float v[5];
        float mx = -3e38f;
#pragma unroll
        for (int nt = 0; nt < 5; nt++) {
            float s = sc[nt][reg] * 0.125f;
            if (nt == 4 && r >= 13) s = -3e38f;  // tokens 77..79 masked
            v[nt] = s;
            mx = fmaxf(mx, s);
        }
#pragma unroll
        for (int off = 1; off < 16; off <<= 1) mx = fmaxf(mx, __shfl_xor(mx, off));
        float sum = 0.f;
#pragma unroll
        for (int nt = 0; nt < 5; nt++) {
            v[nt] = __expf(v[nt] - mx);
            sum += v[nt];
        }
#pragma unroll
        for (int off = 1; off < 16; off <<= 1) sum += __shfl_xor(sum, off);
        const float inv = 1.0f / sum;
#pragma unroll
        for (int nt = 0; nt < 5; nt++)
            Plw[(quad * 4 + reg) * 104 + nt * 16 + r] = f2bf(v[nt] * inv);
    }
    __syncthreads();  // P store -> cross-lane A-frag read
    const short8 ap0 = *(const short8*)&Plw[r * 104 + quad * 8];
    const short8 ap1 = *(const short8*)&Plw[r * 104 + 32 + quad * 8];
    const short8 ap2 = *(const short8*)&Plw[r * 104 + 64 + quad * 8];
#pragma unroll
    for (int nt = 0; nt < 4; nt++) {
        f32x4 z = {0.f, 0.f, 0.f, 0.f};
        const short8 bv0 = *(const short8*)&Vl[(nt * 16 + r) * 104 + quad * 8];
        const short8 bv1 = *(const short8*)&Vl[(nt * 16 + r) * 104 + 32 + quad * 8];
        const short8 bv2 = *(const short8*)&Vl[(nt * 16 + r) * 104 + 64 + quad * 8];
        z = __builtin_amdgcn_mfma_f32_16x16x32_bf16(ap0, bv0, z, 0, 0, 0);
        z = __builtin_amdgcn_mfma_f32_16x16x32_bf16(ap1, bv1, z, 0, 0, 0);
        z = __builtin_amdgcn_mfma_f32_16x16x32_bf16(ap2, bv2, z, 0, 0, 0);
        o[nt] = z;
    }
}

// ---------------------------------------------------------------------------
// Spatial (per batch): grid (16 qc, 16 h, 16 t). Q rows t*1024+hw -> S same.
// ---------------------------------------------------------------------------
__global__ void attn_spatial(const u16* __restrict__ Q, const u16* __restrict__ Kp,
                             const u16* __restrict__ VT, u16* __restrict__ S) {
    const int qc = blockIdx.x, h = blockIdx.y, t = blockIdx.z;
    const int g = h >> 2;
    __shared__ __align__(16) u16 Kl[80 * 72];
    __shared__ __align__(16) u16 Vl[64 * 104];
    __shared__ __align__(16) u16 Pl[4][16 * 104];
    const int tid = threadIdx.x;
    const int wave = tid >> 6, lane = tid & 63, quad = lane >> 4, r = lane & 15;

    const u16* Kg = Kp + (size_t)g * 80 * 64;
    for (int idx = tid; idx < 80 * 64; idx += 256)
        Kl[(idx >> 6) * 72 + (idx & 63)] = Kg[idx];
    const u16* Vg = VT + (size_t)g * 64 * 96;
    for (int idx = tid; idx < 64 * 96; idx += 256) {
        const int d = idx / 96, tk = idx - d * 96;
        Vl[d * 104 + tk] = Vg[idx];
    }
#pragma unroll
    for (int j = 0; j < 4; j++) Pl[wave][r * 104 + 80 + quad * 4 + j] = 0;
    __syncthreads();

    const size_t qrow = (size_t)t * 1024 + qc * 64 + wave * 16 + r;
    const u16* Qb = Q + qrow * 1024 + h * 64;
    const short8 aq0 = *(const short8*)(Qb + quad * 8);
    const short8 aq1 = *(const short8*)(Qb + 32 + quad * 8);

    f32x4 o[4];
    attn_core(aq0, aq1, Kl, Vl, Pl[wave], quad, r, o);

    const size_t srow0 = (size_t)t * 1024 + qc * 64 + wave * 16 + quad * 4;
#pragma unroll
    for (int nt = 0; nt < 4; nt++)
#pragma unroll
        for (int reg = 0; reg < 4; reg++)
            S[(srow0 + reg) * 1024 + h * 64 + nt * 16 + r] = f2bf(o[nt][reg]);
}

// ---------------------------------------------------------------------------
// Temporal (per batch), IN-PLACE on Q.
// ---------------------------------------------------------------------------
__global__ void attn_temporal(u16* Q, const u16* __restrict__ Kp,
                              const u16* __restrict__ VT) {
    const int hw0 = blockIdx.x * 4, h = blockIdx.y;
    const int g = h >> 2;
    __shared__ __align__(16) u16 Kl[80 * 72];
    __shared__ __align__(16) u16 Vl[64 * 104];
    __shared__ __align__(16) u16 Ql[4][16 * 72];
    __shared__ __align__(16) u16 Pl[4][16 * 104];
    const int tid = threadIdx.x;
    const int wave = tid >> 6, lane = tid & 63, quad = lane >> 4, r = lane & 15;

    const u16* Kg = Kp + (size_t)g * 80 * 64;
    for (int idx = tid; idx < 80 * 64; idx += 256)
        Kl[(idx >> 6) * 72 + (idx & 63)] = Kg[idx];
    const u16* Vg = VT + (size_t)g * 64 * 96;
    for (int idx = tid; idx < 64 * 96; idx += 256) {
        const int d = idx / 96, tk = idx - d * 96;
        Vl[d * 104 + tk] = Vg[idx];
    }
    for (int idx = tid; idx < 4096; idx += 256) {
        const int hwl = idx >> 10, t = (idx >> 6) & 15, d = idx & 63;
        Ql[hwl][t * 72 + d] = Q[((size_t)t * 1024 + hw0 + hwl) * 1024 + h * 64 + d];
    }
#pragma unroll
    for (int j = 0; j < 4; j++) Pl[wave][r * 104 + 80 + quad * 4 + j] = 0;
    __syncthreads();

    const short8 aq0 = *(const short8*)&Ql[wave][r * 72 + quad * 8];
    const short8 aq1 = *(const short8*)&Ql[wave][r * 72 + 32 + quad * 8];

    f32x4 o[4];
    attn_core(aq0, aq1, Kl, Vl, Pl[wave], quad, r, o);

    const int hw = hw0 + wave;
#pragma unroll
    for (int nt = 0; nt < 4; nt++)
#pragma unroll
        for (int reg = 0; reg < 4; reg++)
            Q[((size_t)(quad * 4 + reg) * 1024 + hw) * 1024 + h * 64 + nt * 16 + r] =
                f2bf(o[nt][reg]);
}

// ---------------------------------------------------------------------------
// ws layout (bytes), total ~80.2 MB:
//   0         flag (64B)
//   64        WqT   2,097,152
//   2,097,216 WoT   2,097,152
//   4,194,368 Wstc  4,194,304
//   8,388,672 W12T  4,194,304
//  12,898,368 Kp       81,920
//  12,980,288 VT       98,304
//  13,078,592 Q    33,554,432
//  46,633,024 S    33,554,432  (head doubles as pre-loop kv scratch:
//                               textp 512KB | WkvT 1MB | Kall 256KB)
// ---------------------------------------------------------------------------
extern "C" void kernel_launch(void* const* d_in, const int* in_sizes, int n_in,
                              void* d_out, int out_size, void* d_ws, size_t ws_size,
                              hipStream_t stream) {
    const void* x    = d_in[0];
    const void* text = d_in[1];
    const void* Wq   = d_in[5];
    const void* Wk   = d_in[6];
    const void* Wv   = d_in[7];
    const void* Wo   = d_in[8];
    const void* Wst  = d_in[9];
    char* ws = (char*)d_ws;

    int* flag  = (int*)(ws);
    u16* WqT   = (u16*)(ws + 64);
    u16* WoT   = (u16*)(ws + 2097216);
    u16* Wstc  = (u16*)(ws + 4194368);
    u16* W12T  = (u16*)(ws + 8388672);
    u16* Kp    = (u16*)(ws + 12898368);
    u16* VTb   = (u16*)(ws + 12980288);
    u16* Qws   = (u16*)(ws + 13078592);
    u16* Sws   = (u16*)(ws + 46633024);
    // pre-loop scratch inside Sws (consumed before batch loop overwrites it)
    u16* textp = Sws;                       // 256 x 1024 bf16 (512 KB)
    u16* WkvT  = (u16*)(ws + 46633024 + 524288);   // 512 x 1024 bf16 (1 MB)
    u16* Kall  = (u16*)(ws + 46633024 + 1572864);  // 256 x 512 bf16 (256 KB)

    sniff_dtype<<<1, 256, 0, stream>>>((const u16*)Wq, flag);
    cvt_copy8<<<1024, 256, 0, stream>>>(Wst, 0, Wstc, 2097152L, flag);
    transpose_cvt<<<dim3(32, 32), dim3(32, 8), 0, stream>>>(Wq, WqT, flag);
    transpose_cvt<<<dim3(32, 32), dim3(32, 8), 0, stream>>>(Wo, WoT, flag);
    // W12T[n][k'] = (Wst @ Wo)[k'][n]  (M=1024, N=2048, K=1024)
    gemm_bt<<<dim3(16, 8), 256, 0, stream>>>(WoT, Wstc, W12T, 1024, 1024, 1024, 2048);

    // ---- K/V projection as a small MFMA GEMM (replaces latency-bound prep_kv)
    transpose_kv<<<dim3(8, 32), dim3(32, 8), 0, stream>>>(Wk, WkvT, flag);
    transpose_kv<<<dim3(8, 32), dim3(32, 8), 0, stream>>>(Wv, WkvT + 256 * 1024, flag);
    cvt_pad_text<<<256, 128, 0, stream>>>(text, textp, flag);
    // Kall[256][512] = textp @ [Wk|Wv]  (M=256 incl. zero pad rows, N=512, K=1024)
    gemm_bt<<<dim3(4, 2), 256, 0, stream>>>(textp, WkvT, Kall, 1024, 1024, 1024, 512);
    repack_kv<<<dim3(4, 2), 256, 0, stream>>>(Kall, Kp, VTb);

    for (int b = 0; b < 2; b++) {
        const long xbase = (long)b * 16777216;
        const u16* Kpb = Kp + (size_t)b * 20480;
        const u16* VTp = VTb + (size_t)b * 24576;

        // x_b -> bf16 scratch (Sws; consumed by gemm256<0> before attn
        // overwrites it with S)
        cvt_copy8<<<2048, 256, 0, stream>>>(x, xbase, Sws, 16777216L, flag);
        // Q_b = xc @ Wq  (256^2 deep-pipelined)
        gemm256<0><<<dim3(4, 64), 512, 0, stream>>>(Sws, nullptr, WqT, Qws, 0, flag);
        // spatial attention: Q -> S (Sws)
        attn_spatial<<<dim3(16, 16, 16), 256, 0, stream>>>(Qws, Kpb, VTp, Sws);
        // temporal attention: in-place Q -> Tm
        attn_temporal<<<dim3(256, 16), 256, 0, stream>>>(Qws, Kpb, VTp);
        // out_b = S@W1 + Tm@W2 (256^2 deep-pipelined, writes d_out only)
        gemm256<1><<<dim3(4, 64), 512, 0, stream>>>(Sws, Qws, W12T, d_out, xbase, flag);
    }
}

// Round 7
// 739.913 us; speedup vs baseline: 1.4016x; 1.0575x over previous
//
#include <hip/hip_runtime.h>

typedef unsigned short u16;
typedef __attribute__((ext_vector_type(8))) short short8;
typedef __attribute__((ext_vector_type(4))) float f32x4;

__device__ __forceinline__ u16 f2bf(float f) {
    unsigned u = __builtin_bit_cast(unsigned, f);
    u += 0x7FFFu + ((u >> 16) & 1u);
    return (u16)(u >> 16);
}
__device__ __forceinline__ float bf2f(u16 h) {
    unsigned u = ((unsigned)h) << 16;
    return __builtin_bit_cast(float, u);
}

#define GLD_LDS(g, l) \
    __builtin_amdgcn_global_load_lds((const __attribute__((address_space(1))) void*)(g), \
                                     (__attribute__((address_space(3))) void*)(l), 16, 0, 0)

// Counted vmcnt (T4): keep prefetch in flight across barriers.
#define WAITV(n) asm volatile("s_waitcnt vmcnt(" #n ")" ::: "memory")
// Raw barrier with compiler memory fences on both sides (no vmcnt drain).
#define BARM()                                  \
    do {                                        \
        asm volatile("" ::: "memory");          \
        __builtin_amdgcn_s_barrier();           \
        asm volatile("" ::: "memory");          \
    } while (0)

// XCD-aware bijective block swizzle (T1). XCD == flat % 8; remap so each XCD
// owns a contiguous chunk of tiles. Requires nwg % 8 == 0.
__device__ __forceinline__ void xcd_swizzle(int& bx, int& by) {
    const int nwg = gridDim.x * gridDim.y;
    const int flat = blockIdx.y * gridDim.x + blockIdx.x;
    const int cpx = nwg >> 3;
    const int nf = (flat & 7) * cpx + (flat >> 3);
    bx = nf % gridDim.x;
    by = nf / gridDim.x;
}

// ---------------------------------------------------------------------------
// Dtype sniff: flag=1 -> inputs are float32; flag=0 -> inputs are bf16.
// ---------------------------------------------------------------------------
__global__ void sniff_dtype(const u16* __restrict__ wq, int* __restrict__ flag) {
    __shared__ int cnt;
    if (threadIdx.x == 0) cnt = 0;
    __syncthreads();
    int local = 0;
    for (int i = threadIdx.x; i < 1024; i += 256) {
        const int e = (wq[i] >> 7) & 0xFF;
        if (e >= 0x81) local++;
    }
    atomicAdd(&cnt, local);
    __syncthreads();
    if (threadIdx.x == 0) *flag = (cnt >= 32) ? 1 : 0;
}

// ---------------------------------------------------------------------------
// Vectorized convert-or-copy with element offset. n multiple of 8.
// ---------------------------------------------------------------------------
__global__ void cvt_copy8(const void* __restrict__ in, long off,
                          u16* __restrict__ out, long n,
                          const int* __restrict__ flag) {
    const long stride = (long)gridDim.x * 256 * 8;
    long i = ((long)blockIdx.x * 256 + threadIdx.x) * 8;
    if (*flag) {
        const float* p = (const float*)in + off;
        for (; i < n; i += stride) {
            const f32x4 a = *(const f32x4*)(p + i);
            const f32x4 b = *(const f32x4*)(p + i + 4);
            short8 h;
#pragma unroll
            for (int j = 0; j < 4; j++) {
                h[j] = (short)f2bf(a[j]);
                h[j + 4] = (short)f2bf(b[j]);
            }
            *(short8*)(out + i) = h;
        }
    } else {
        const u16* p = (const u16*)in + off;
        for (; i < n; i += stride) *(short8*)(out + i) = *(const short8*)(p + i);
    }
}

// ---------------------------------------------------------------------------
// 1024x1024 transpose with convert-to-bf16
// ---------------------------------------------------------------------------
__global__ void transpose_cvt(const void* __restrict__ in, u16* __restrict__ out,
                              const int* __restrict__ flag) {
    __shared__ u16 t[32][33];
    const int x0 = blockIdx.x * 32, y0 = blockIdx.y * 32;
    const int tx = threadIdx.x, ty = threadIdx.y;
    if (*flag) {
        const float* p = (const float*)in;
        for (int dy = ty; dy < 32; dy += 8)
            t[dy][tx] = f2bf(p[(size_t)(y0 + dy) * 1024 + x0 + tx]);
    } else {
        const u16* p = (const u16*)in;
        for (int dy = ty; dy < 32; dy += 8)
            t[dy][tx] = p[(size_t)(y0 + dy) * 1024 + x0 + tx];
    }
    __syncthreads();
    for (int dy = ty; dy < 32; dy += 8)
        out[(size_t)(x0 + dy) * 1024 + y0 + tx] = t[tx][dy];
}

// ---------------------------------------------------------------------------
// Wk/Wv transpose: in [1024 rows][256 cols] (dtype per flag) -> out[256][1024]
// bf16. Grid (8, 32), block (32, 8).
// ---------------------------------------------------------------------------
__global__ void transpose_kv(const void* __restrict__ in, u16* __restrict__ out,
                             const int* __restrict__ flag) {
    __shared__ u16 t[32][33];
    const int x0 = blockIdx.x * 32, y0 = blockIdx.y * 32;  // x: col, y: row
    const int tx = threadIdx.x, ty = threadIdx.y;
    if (*flag) {
        const float* p = (const float*)in;
        for (int dy = ty; dy < 32; dy += 8)
            t[dy][tx] = f2bf(p[(size_t)(y0 + dy) * 256 + x0 + tx]);
    } else {
        const u16* p = (const u16*)in;
        for (int dy = ty; dy < 32; dy += 8)
            t[dy][tx] = p[(size_t)(y0 + dy) * 256 + x0 + tx];
    }
    __syncthreads();
    for (int dy = ty; dy < 32; dy += 8)
        out[(size_t)(x0 + dy) * 1024 + y0 + tx] = t[tx][dy];
}

// ---------------------------------------------------------------------------
// text -> textp[2*128][1024] bf16, rows 77..127 of each batch zeroed.
// ---------------------------------------------------------------------------
__global__ void cvt_pad_text(const void* __restrict__ in, u16* __restrict__ out,
                             const int* __restrict__ flag) {
    const int row = blockIdx.x, b = row >> 7, t = row & 127;
    const int j = threadIdx.x * 8;
    short8 h = {0, 0, 0, 0, 0, 0, 0, 0};
    if (t < 77) {
        if (*flag) {
            const float* p = (const float*)in + ((size_t)(b * 77 + t)) * 1024 + j;
            const f32x4 a = *(const f32x4*)p;
            const f32x4 c = *(const f32x4*)(p + 4);
#pragma unroll
            for (int k = 0; k < 4; k++) {
                h[k] = (short)f2bf(a[k]);
                h[k + 4] = (short)f2bf(c[k]);
            }
        } else {
            h = *(const short8*)((const u16*)in + ((size_t)(b * 77 + t)) * 1024 + j);
        }
    }
    *(short8*)&out[(size_t)row * 1024 + j] = h;
}

// ---------------------------------------------------------------------------
// Kall[256][512] -> Kp[b][g][80][64], VT[b][g][64][96]. Grid (4 g, 2 b).
// ---------------------------------------------------------------------------
__global__ void repack_kv(const u16* __restrict__ Kall, u16* __restrict__ Kp,
                          u16* __restrict__ VT) {
    const int g = blockIdx.x, b = blockIdx.y;
    const int tid = threadIdx.x;
    for (int idx = tid; idx < 80 * 64; idx += 256) {
        const int tok = idx >> 6, d = idx & 63;
        Kp[((size_t)(b * 4 + g) * 80 + tok) * 64 + d] =
            Kall[(size_t)(b * 128 + tok) * 512 + g * 64 + d];
    }
    for (int idx = tid; idx < 64 * 96; idx += 256) {
        const int d = idx / 96, tok = idx - d * 96;
        VT[(size_t)(b * 4 + g) * 6144 + d * 96 + tok] =
            Kall[(size_t)(b * 128 + tok) * 512 + 256 + g * 64 + d];
    }
}

// ---------------------------------------------------------------------------
// bf16 GEMM (small precomputes): C[M,N] = A[M,K] @ BT[N,K]^T.
// 128x128 tile, BK=32, 4 waves. Proven 2-syncthreads form.
// ---------------------------------------------------------------------------
__global__ void gemm_bt(const u16* __restrict__ A, const u16* __restrict__ BT,
                        u16* __restrict__ C, int K, int lda, int ldb, int ldc) {
    __shared__ __align__(16) u16 As[512 * 8];
    __shared__ __align__(16) u16 Bs[512 * 8];
    const int tid = threadIdx.x;
    const int wave = tid >> 6, lane = tid & 63, quad = lane >> 4, r = lane & 15;
    const int wm = (wave >> 1) * 64, wn = (wave & 1) * 64;
    int bx, by;
    xcd_swizzle(bx, by);
    const long m0 = (long)by * 128, n0 = (long)bx * 128;

    f32x4 acc[4][4] = {};
    const int c0 = wave * 64 + lane, c1 = (wave + 4) * 64 + lane;
    const int kc0 = c0 >> 7, mm0 = c0 & 127, kc1 = c1 >> 7, mm1 = c1 & 127;
    const u16* ga0 = A + (m0 + mm0) * (long)lda + kc0 * 8;
    const u16* ga1 = A + (m0 + mm1) * (long)lda + kc1 * 8;
    const u16* gb0 = BT + (n0 + mm0) * (long)ldb + kc0 * 8;
    const u16* gb1 = BT + (n0 + mm1) * (long)ldb + kc1 * 8;

    for (int k0 = 0; k0 < K; k0 += 32) {
        GLD_LDS(ga0 + k0, &As[wave * 64 * 8]);
        GLD_LDS(ga1 + k0, &As[(wave + 4) * 64 * 8]);
        GLD_LDS(gb0 + k0, &Bs[wave * 64 * 8]);
        GLD_LDS(gb1 + k0, &Bs[(wave + 4) * 64 * 8]);
        __syncthreads();
        short8 af[4], bfr[4];
#pragma unroll
        for (int mt = 0; mt < 4; mt++)
            af[mt] = *(const short8*)&As[(quad * 128 + wm + mt * 16 + r) * 8];
#pragma unroll
        for (int nt = 0; nt < 4; nt++)
            bfr[nt] = *(const short8*)&Bs[(quad * 128 + wn + nt * 16 + r) * 8];
#pragma unroll
        for (int mt = 0; mt < 4; mt++)
#pragma unroll
            for (int nt = 0; nt < 4; nt++)
                acc[mt][nt] = __builtin_amdgcn_mfma_f32_16x16x32_bf16(
                    af[mt], bfr[nt], acc[mt][nt], 0, 0, 0);
        __syncthreads();
    }
#pragma unroll
    for (int mt = 0; mt < 4; mt++)
#pragma unroll
        for (int nt = 0; nt < 4; nt++)
#pragma unroll
            for (int reg = 0; reg < 4; reg++) {
                const long row = m0 + wm + mt * 16 + quad * 4 + reg;
                const long col = n0 + wn + nt * 16 + r;
                C[row * (long)ldc + col] = f2bf(acc[mt][nt][reg]);
            }
}

// ---------------------------------------------------------------------------
// Stage one K-half (kh) of a 256x64 tile: 256 rows x 32 k = 16KB, chunks
// kc = kh*4..kh*4+3 -> contiguous LDS region [kh*1024*8, (kh+1)*1024*8).
// 2 GLD per lane. The trailing compiler-only fence pins GLD issue ORDER
// (vmcnt FIFO accounting depends on program-order issue; LLVM must not
// reorder independent global_load_lds across stage units).
// ---------------------------------------------------------------------------
__device__ __forceinline__ void stage_kh(const u16* __restrict__ src, long ld,
                                         u16* lds, int kh, int wave, int lane) {
#pragma unroll
    for (int j = 0; j < 2; j++) {
        const int idx0 = j * 512 + wave * 64;
        const int kc = kh * 4 + (idx0 >> 8), row0 = idx0 & 255;
        GLD_LDS(src + (long)(row0 + lane) * ld + kc * 8,
                lds + (kh * 1024 + idx0) * 8);
    }
    asm volatile("" ::: "memory");
}

// ---------------------------------------------------------------------------
// 256x256-tile deep-pipelined bf16 GEMM — K-half phase schedule.
// MODE 0 (Q proj): C = A1[16384,1024] @ BT[1024,1024]^T, bf16 out.
// MODE 1 (final):  out = S@W1 + Tm@W2 via A = [A1 | A2], BT[1024,2048], K=2048.
// 512 threads = 8 waves (2M x 4N); per-wave output 128x64; LDS 128KB dbuf.
//
// Per 64-K tile t (buf c=t&1), 4 phases consume stage-units IN STAGING ORDER
// so every unit gets 3-4 phases of latency coverage (m201 pattern):
//   ph0: stage A-Kh0(t+1); vmcnt(6) [waits A/B-Kh0(t)]; BAR; mb0-3 x Kh0
//   ph1: stage B-Kh0(t+1);                                mb4-7 x Kh0
//   ph2: stage A-Kh1(t+1); vmcnt(6) [waits A/B-Kh1(t)]; BAR; mb0-3 x Kh1
//   ph3: stage B-Kh1(t+1);                                mb4-7 x Kh1
//   BAR (end-of-tile WAR fence)
// vmcnt never drains to 0 mid-loop; counts audited against FIFO order
// (prologue + per-tile staging order identical: A-Kh0, B-Kh0, A-Kh1, B-Kh1).
// ---------------------------------------------------------------------------
template <int MODE>
__global__ __launch_bounds__(512, 2) void gemm256(
    const u16* __restrict__ A1, const u16* __restrict__ A2,
    const u16* __restrict__ BT, void* __restrict__ outv, long base,
    const int* __restrict__ flag) {
    __shared__ __align__(16) u16 As[2][8 * 256 * 8];
    __shared__ __align__(16) u16 Bs[2][8 * 256 * 8];
    const int tid = threadIdx.x;
    const int wave = tid >> 6, lane = tid & 63, quad = lane >> 4, r = lane & 15;
    const int wr = wave >> 2, wc = wave & 3;
    int bx, by;
    xcd_swizzle(bx, by);
    const long m0 = (long)by * 256, n0 = (long)bx * 256;
    const int ldb = MODE ? 2048 : 1024;
    const int NT = MODE ? 32 : 16;

    f32x4 acc[8][4] = {};

    auto asrc = [&](int tt) -> const u16* {
        if (MODE == 0) return A1 + m0 * 1024 + (long)tt * 64;
        return (tt < 16) ? (A1 + m0 * 1024 + (long)tt * 64)
                         : (A2 + m0 * 1024 + (long)(tt - 16) * 64);
    };
    const u16* bbase = BT + n0 * (long)ldb;

    // prologue: tile 0 into buffer 0, in canonical unit order
    stage_kh(asrc(0), 1024, As[0], 0, wave, lane);
    stage_kh(bbase, ldb, Bs[0], 0, wave, lane);
    stage_kh(asrc(0), 1024, As[0], 1, wave, lane);
    stage_kh(bbase, ldb, Bs[0], 1, wave, lane);

#define PH_READ_B(kh)                                                         \
    _Pragma("unroll") for (int nt = 0; nt < 4; nt++)                          \
        bf[nt] = *(const short8*)&Bs[c][(((kh) * 4 + quad) * 256 +            \
                                         wc * 64 + nt * 16 + r) * 8];
#define PH_READ_A(kh, mb0)                                                    \
    _Pragma("unroll") for (int mi = 0; mi < 4; mi++)                          \
        afx[mi] = *(const short8*)&As[c][(((kh) * 4 + quad) * 256 +           \
                                          wr * 128 + ((mb0) + mi) * 16 + r) * 8];
#define PH_MFMA(mb0)                                                          \
    __builtin_amdgcn_s_setprio(1);                                            \
    _Pragma("unroll") for (int mi = 0; mi < 4; mi++)                          \
        _Pragma("unroll") for (int nt = 0; nt < 4; nt++)                      \
            acc[(mb0) + mi][nt] = __builtin_amdgcn_mfma_f32_16x16x32_bf16(    \
                afx[mi], bf[nt], acc[(mb0) + mi][nt], 0, 0, 0);               \
    __builtin_amdgcn_s_setprio(0);

#pragma unroll 2
    for (int t = 0; t < NT; t++) {
        const int c = t & 1, n = c ^ 1;
        const bool have = (t + 1 < NT);
        const u16* an = asrc(have ? t + 1 : t);
        const u16* bn = bbase + (long)(t + 1) * 64;
        short8 bf[4], afx[4];
        // ph0
        if (have) {
            stage_kh(an, 1024, As[n], 0, wave, lane);
            WAITV(6);
        } else {
            WAITV(4);
        }
        BARM();
        PH_READ_B(0);
        PH_READ_A(0, 0);
        PH_MFMA(0);
        // ph1
        PH_READ_A(0, 4);
        if (have) stage_kh(bn, ldb, Bs[n], 0, wave, lane);
        PH_MFMA(4);
        // ph2
        if (have) {
            stage_kh(an, 1024, As[n], 1, wave, lane);
            WAITV(6);
        } else {
            WAITV(0);
        }
        BARM();
        PH_READ_B(1);
        PH_READ_A(1, 0);
        PH_MFMA(0);
        // ph3
        PH_READ_A(1, 4);
        if (have) stage_kh(bn, ldb, Bs[n], 1, wave, lane);
        PH_MFMA(4);
        BARM();
    }
#undef PH_READ_B
#undef PH_READ_A
#undef PH_MFMA

    if (MODE == 0) {
        u16* o = (u16*)outv;
#pragma unroll
        for (int mt = 0; mt < 8; mt++)
#pragma unroll
            for (int nt = 0; nt < 4; nt++)
#pragma unroll
                for (int reg = 0; reg < 4; reg++)
                    o[(m0 + wr * 128 + mt * 16 + quad * 4 + reg) * 1024L + n0 +
                      wc * 64 + nt * 16 + r] = f2bf(acc[mt][nt][reg]);
    } else if (*flag) {
        float* o = (float*)outv + base;
#pragma unroll
        for (int mt = 0; mt < 8; mt++)
#pragma unroll
            for (int nt = 0; nt < 4; nt++)
#pragma unroll
                for (int reg = 0; reg < 4; reg++)
                    o[(m0 + wr * 128 + mt * 16 + quad * 4 + reg) * 1024L + n0 +
                      wc * 64 + nt * 16 + r] = acc[mt][nt][reg];
    } else {
        u16* o = (u16*)outv + base;
#pragma unroll
        for (int mt = 0; mt < 8; mt++)
#pragma unroll
            for (int nt = 0; nt < 4; nt++)
#pragma unroll
                for (int reg = 0; reg < 4; reg++)
                    o[(m0 + wr * 128 + mt * 16 + quad * 4 + reg) * 1024L + n0 +
                      wc * 64 + nt * 16 + r] = f2bf(acc[mt][nt][reg]);
    }
}

// ---------------------------------------------------------------------------
// Attention core per wave: 16 queries x 77 tokens x one head.
// ---------------------------------------------------------------------------
__device__ __forceinline__ void attn_core(const short8 aq0, const short8 aq1,
                                          const u16* Kl, const u16* Vl, u16* Plw,
                                          const int quad, const int r, f32x4 o[4]) {
    f32x4 sc[5];
#pragma unroll
    for (int nt = 0; nt < 5; nt++) {
        f32x4 z = {0.f, 0.f, 0.f, 0.f};
        const short8 bk0 = *(const short8*)&Kl[(nt * 16 + r) * 72 + quad * 8];
        const short8 bk1 = *(const short8*)&Kl[(nt * 16 + r) * 72 + 32 + quad * 8];
        z = __builtin_amdgcn_mfma_f32_16x16x32_bf16(aq0, bk0, z, 0, 0, 0);
        z = __builtin_amdgcn_mfma_f32_16x16x32_bf16(aq1, bk1, z, 0, 0, 0);
        sc[nt] = z;
    }
#pragma unroll
    for (int reg = 0; reg < 4; reg++) {
        float v[5];
        float mx = -3e38f;
#pragma unroll
        for (int nt = 0; nt < 5; nt++) {
            float s = sc[nt][reg] * 0.125f;
            if (nt == 4 && r >= 13) s = -3e38f;  // tokens 77..79 masked
            v[nt] = s;
            mx = fmaxf(mx, s);
        }
#pragma unroll
        for (int off = 1; off < 16; off <<= 1) mx = fmaxf(mx, __shfl_xor(mx, off));
        float sum = 0.f;
#pragma unroll
        for (int nt = 0; nt < 5; nt++) {
            v[nt] = __expf(v[nt] - mx);
            sum += v[nt];
        }
#pragma unroll
        for (int off = 1; off < 16; off <<= 1) sum += __shfl_xor(sum, off);
        const float inv = 1.0f / sum;
#pragma unroll
        for (int nt = 0; nt < 5; nt++)
            Plw[(quad * 4 + reg) * 104 + nt * 16 + r] = f2bf(v[nt] * inv);
    }
    __syncthreads();  // P store -> cross-lane A-frag read
    const short8 ap0 = *(const short8*)&Plw[r * 104 + quad * 8];
    const short8 ap1 = *(const short8*)&Plw[r * 104 + 32 + quad * 8];
    const short8 ap2 = *(const short8*)&Plw[r * 104 + 64 + quad * 8];
#pragma unroll
    for (int nt = 0; nt < 4; nt++) {
        f32x4 z = {0.f, 0.f, 0.f, 0.f};
        const short8 bv0 = *(const short8*)&Vl[(nt * 16 + r) * 104 + quad * 8];
        const short8 bv1 = *(const short8*)&Vl[(nt * 16 + r) * 104 + 32 + quad * 8];
        const short8 bv2 = *(const short8*)&Vl[(nt * 16 + r) * 104 + 64 + quad * 8];
        z = __builtin_amdgcn_mfma_f32_16x16x32_bf16(ap0, bv0, z, 0, 0, 0);
        z = __builtin_amdgcn_mfma_f32_16x16x32_bf16(ap1, bv1, z, 0, 0, 0);
        z = __builtin_amdgcn_mfma_f32_16x16x32_bf16(ap2, bv2, z, 0, 0, 0);
        o[nt] = z;
    }
}

// ---------------------------------------------------------------------------
// Spatial (per batch): grid (16 qc, 16 h, 16 t). Q rows t*1024+hw -> S same.
// ---------------------------------------------------------------------------
__global__ void attn_spatial(const u16* __restrict__ Q, const u16* __restrict__ Kp,
                             const u16* __restrict__ VT, u16* __restrict__ S) {
    const int qc = blockIdx.x, h = blockIdx.y, t = blockIdx.z;
    const int g = h >> 2;
    __shared__ __align__(16) u16 Kl[80 * 72];
    __shared__ __align__(16) u16 Vl[64 * 104];
    __shared__ __align__(16) u16 Pl[4][16 * 104];
    const int tid = threadIdx.x;
    const int wave = tid >> 6, lane = tid & 63, quad = lane >> 4, r = lane & 15;

    const u16* Kg = Kp + (size_t)g * 80 * 64;
    for (int idx = tid; idx < 80 * 64; idx += 256)
        Kl[(idx >> 6) * 72 + (idx & 63)] = Kg[idx];
    const u16* Vg = VT + (size_t)g * 64 * 96;
    for (int idx = tid; idx < 64 * 96; idx += 256) {
        const int d = idx / 96, tk = idx - d * 96;
        Vl[d * 104 + tk] = Vg[idx];
    }
#pragma unroll
    for (int j = 0; j < 4; j++) Pl[wave][r * 104 + 80 + quad * 4 + j] = 0;
    __syncthreads();

    const size_t qrow = (size_t)t * 1024 + qc * 64 + wave * 16 + r;
    const u16* Qb = Q + qrow * 1024 + h * 64;
    const short8 aq0 = *(const short8*)(Qb + quad * 8);
    const short8 aq1 = *(const short8*)(Qb + 32 + quad * 8);

    f32x4 o[4];
    attn_core(aq0, aq1, Kl, Vl, Pl[wave], quad, r, o);

    const size_t srow0 = (size_t)t * 1024 + qc * 64 + wave * 16 + quad * 4;
#pragma unroll
    for (int nt = 0; nt < 4; nt++)
#pragma unroll
        for (int reg = 0; reg < 4; reg++)
            S[(srow0 + reg) * 1024 + h * 64 + nt * 16 + r] = f2bf(o[nt][reg]);
}

// ---------------------------------------------------------------------------
// Temporal (per batch), IN-PLACE on Q.
// ---------------------------------------------------------------------------
__global__ void attn_temporal(u16* Q, const u16* __restrict__ Kp,
                              const u16* __restrict__ VT) {
    const int hw0 = blockIdx.x * 4, h = blockIdx.y;
    const int g = h >> 2;
    __shared__ __align__(16) u16 Kl[80 * 72];
    __shared__ __align__(16) u16 Vl[64 * 104];
    __shared__ __align__(16) u16 Ql[4][16 * 72];
    __shared__ __align__(16) u16 Pl[4][16 * 104];
    const int tid = threadIdx.x;
    const int wave = tid >> 6, lane = tid & 63, quad = lane >> 4, r = lane & 15;

    const u16* Kg = Kp + (size_t)g * 80 * 64;
    for (int idx = tid; idx < 80 * 64; idx += 256)
        Kl[(idx >> 6) * 72 + (idx & 63)] = Kg[idx];
    const u16* Vg = VT + (size_t)g * 64 * 96;
    for (int idx = tid; idx < 64 * 96; idx += 256) {
        const int d = idx / 96, tk = idx - d * 96;
        Vl[d * 104 + tk] = Vg[idx];
    }
    for (int idx = tid; idx < 4096; idx += 256) {
        const int hwl = idx >> 10, t = (idx >> 6) & 15, d = idx & 63;
        Ql[hwl][t * 72 + d] = Q[((size_t)t * 1024 + hw0 + hwl) * 1024 + h * 64 + d];
    }
#pragma unroll
    for (int j = 0; j < 4; j++) Pl[wave][r * 104 + 80 + quad * 4 + j] = 0;
    __syncthreads();

    const short8 aq0 = *(const short8*)&Ql[wave][r * 72 + quad * 8];
    const short8 aq1 = *(const short8*)&Ql[wave][r * 72 + 32 + quad * 8];

    f32x4 o[4];
    attn_core(aq0, aq1, Kl, Vl, Pl[wave], quad, r, o);

    const int hw = hw0 + wave;
#pragma unroll
    for (int nt = 0; nt < 4; nt++)
#pragma unroll
        for (int reg = 0; reg < 4; reg++)
            Q[((size_t)(quad * 4 + reg) * 1024 + hw) * 1024 + h * 64 + nt * 16 + r] =
                f2bf(o[nt][reg]);
}

// ---------------------------------------------------------------------------
// ws layout (bytes), total ~80.2 MB:
//   0         flag (64B)
//   64        WqT   2,097,152
//   2,097,216 WoT   2,097,152
//   4,194,368 Wstc  4,194,304
//   8,388,672 W12T  4,194,304
//  12,898,368 Kp       81,920
//  12,980,288 VT       98,304
//  13,078,592 Q    33,554,432
//  46,633,024 S    33,554,432  (head doubles as pre-loop kv scratch:
//                               textp 512KB | WkvT 1MB | Kall 256KB)
// ---------------------------------------------------------------------------
extern "C" void kernel_launch(void* const* d_in, const int* in_sizes, int n_in,
                              void* d_out, int out_size, void* d_ws, size_t ws_size,
                              hipStream_t stream) {
    const void* x    = d_in[0];
    const void* text = d_in[1];
    const void* Wq   = d_in[5];
    const void* Wk   = d_in[6];
    const void* Wv   = d_in[7];
    const void* Wo   = d_in[8];
    const void* Wst  = d_in[9];
    char* ws = (char*)d_ws;

    int* flag  = (int*)(ws);
    u16* WqT   = (u16*)(ws + 64);
    u16* WoT   = (u16*)(ws + 2097216);
    u16* Wstc  = (u16*)(ws + 4194368);
    u16* W12T  = (u16*)(ws + 8388672);
    u16* Kp    = (u16*)(ws + 12898368);
    u16* VTb   = (u16*)(ws + 12980288);
    u16* Qws   = (u16*)(ws + 13078592);
    u16* Sws   = (u16*)(ws + 46633024);
    // pre-loop scratch inside Sws (consumed before batch loop overwrites it)
    u16* textp = Sws;                                  // 256 x 1024 bf16
    u16* WkvT  = (u16*)(ws + 46633024 + 524288);       // 512 x 1024 bf16
    u16* Kall  = (u16*)(ws + 46633024 + 1572864);      // 256 x 512 bf16

    sniff_dtype<<<1, 256, 0, stream>>>((const u16*)Wq, flag);
    cvt_copy8<<<1024, 256, 0, stream>>>(Wst, 0, Wstc, 2097152L, flag);
    transpose_cvt<<<dim3(32, 32), dim3(32, 8), 0, stream>>>(Wq, WqT, flag);
    transpose_cvt<<<dim3(32, 32), dim3(32, 8), 0, stream>>>(Wo, WoT, flag);
    // W12T[n][k'] = (Wst @ Wo)[k'][n]  (M=1024, N=2048, K=1024)
    gemm_bt<<<dim3(16, 8), 256, 0, stream>>>(WoT, Wstc, W12T, 1024, 1024, 1024, 2048);

    // ---- K/V projection as a small MFMA GEMM
    transpose_kv<<<dim3(8, 32), dim3(32, 8), 0, stream>>>(Wk, WkvT, flag);
    transpose_kv<<<dim3(8, 32), dim3(32, 8), 0, stream>>>(Wv, WkvT + 256 * 1024, flag);
    cvt_pad_text<<<256, 128, 0, stream>>>(text, textp, flag);
    gemm_bt<<<dim3(4, 2), 256, 0, stream>>>(textp, WkvT, Kall, 1024, 1024, 1024, 512);
    repack_kv<<<dim3(4, 2), 256, 0, stream>>>(Kall, Kp, VTb);

    for (int b = 0; b < 2; b++) {
        const long xbase = (long)b * 16777216;
        const u16* Kpb = Kp + (size_t)b * 20480;
        const u16* VTp = VTb + (size_t)b * 24576;

        // x_b -> bf16 scratch (Sws; consumed by gemm256<0> before attn
        // overwrites it with S)
        cvt_copy8<<<2048, 256, 0, stream>>>(x, xbase, Sws, 16777216L, flag);
        // Q_b = xc @ Wq  (256^2 deep-pipelined)
        gemm256<0><<<dim3(4, 64), 512, 0, stream>>>(Sws, nullptr, WqT, Qws, 0, flag);
        // spatial attention: Q -> S (Sws)
        attn_spatial<<<dim3(16, 16, 16), 256, 0, stream>>>(Qws, Kpb, VTp, Sws);
        // temporal attention: in-place Q -> Tm
        attn_temporal<<<dim3(256, 16), 256, 0, stream>>>(Qws, Kpb, VTp);
        // out_b = S@W1 + Tm@W2 (256^2 deep-pipelined, writes d_out only)
        gemm256<1><<<dim3(4, 64), 512, 0, stream>>>(Sws, Qws, W12T, d_out, xbase, flag);
    }
}